// Round 1
// baseline (521.488 us; speedup 1.0000x reference)
//
#include <hip/hip_runtime.h>
#include <hip/hip_bf16.h>

// Problem constants
#define BB 8
#define HH 192
#define WW 192
#define CC0 64
#define NPIX (BB*HH*WW) // 294912
#define NCV 81
#define CVP 96          // cv padded channels in fallback layout

typedef __attribute__((ext_vector_type(8))) short short8;
typedef __attribute__((ext_vector_type(4))) short short4v;
typedef __attribute__((ext_vector_type(4))) float f32x4;

__device__ __forceinline__ float bf2f(short s) {
    union { unsigned u; float f; } x; x.u = ((unsigned)(unsigned short)s) << 16; return x.f;
}
__device__ __forceinline__ short f2bf(float f) {
    __hip_bfloat16 h = __float2bfloat16(f);
    return *reinterpret_cast<short*>(&h);
}
__device__ __forceinline__ void cvt8(const short8 iv, float* fv) {
    const int* ip = (const int*)&iv;
#pragma unroll
    for (int e = 0; e < 4; ++e) {
        union { unsigned u; float f; } lo, hi;
        lo.u = ((unsigned)ip[e]) << 16;
        hi.u = ((unsigned)ip[e]) & 0xffff0000u;
        fv[2 * e] = lo.f; fv[2 * e + 1] = hi.f;
    }
}

__device__ __forceinline__ float mish_f(float v) {
    if (v > 20.0f) return v;
    const float u = __expf(v);
    const float n = u * (u + 2.0f);
    return v * n / (n + 2.0f);
}

// ---------------------------------------------------------------------------
// Weight prep (bf16 Bt matrices, channel order [prv|nxt|cv|pad]) — as R4.
// ---------------------------------------------------------------------------
__global__ __launch_bounds__(256) void prep_kernel(
    const float* __restrict__ dw0, const float* __restrict__ pw0,
    const float* __restrict__ dw1, const float* __restrict__ pw1,
    const float* __restrict__ dw2, const float* __restrict__ pw2,
    const float* __restrict__ dw3, const float* __restrict__ pw3,
    __hip_bfloat16* __restrict__ wout)
{
    const int u = blockIdx.x * 256 + threadIdx.x;
    if (u >= 43456) return;
    float v = 0.f;
    if (u < 2016) {                     // legacy dwbf0 slot (unused, kept for layout)
        const int t = u / 224, c = u % 224;
        if (c < 64)       v = dw0[t*209 + 81  + c];
        else if (c < 128) v = dw0[t*209 + 145 + (c-64)];
        else if (c < 209) v = dw0[t*209 + (c-128)];
    } else if (u < 3168) {
        const int r = u-2016, t = r/128, c = r%128; v = dw1[t*128+c];
    } else if (u < 3744) {
        const int r = u-3168, t = r/64, c = r%64; v = dw2[t*64+c];
    } else if (u < 4032) {
        const int r = u-3744, t = r/32, c = r%32; v = dw3[t*32+c];
    } else if (u < 32704) {             // Bt0 [128][224]
        const int r = u-4032, n = r/224, c = r%224;
        if (c < 64)       v = pw0[(81+c)*128 + n];
        else if (c < 128) v = pw0[(145+(c-64))*128 + n];
        else if (c < 209) v = pw0[(c-128)*128 + n];
    } else if (u < 40896) {             // Bt1 [64][128]
        const int r = u-32704, n = r/128, c = r%128; v = pw1[c*64 + n];
    } else if (u < 42944) {             // Bt2 [32][64]
        const int r = u-40896, n = r/64, c = r%64; v = pw2[c*32 + n];
    } else {                            // Bt3 [16][32]
        const int r = u-42944, n = r/32, c = r%32; v = pw3[c*16 + n];
    }
    wout[u] = __float2bfloat16(v);
}

// ---------------------------------------------------------------------------
// prep2: f32 dw weights (stage0 permuted to [prv|nxt|cv|pad]) + fused BN*flow
// weights. fout: dwf0[2016] dwf1[1152] dwf2[576] dwf3[288] fwp[288] tb[18]
// ---------------------------------------------------------------------------
__global__ __launch_bounds__(256) void prep2_kernel(
    const float* __restrict__ dw0, const float* __restrict__ dw1,
    const float* __restrict__ dw2, const float* __restrict__ dw3,
    const float* __restrict__ bn_g, const float* __restrict__ bn_b,
    const float* __restrict__ bn_m, const float* __restrict__ bn_v,
    const float* __restrict__ fw, float* __restrict__ fout)
{
    const int u = blockIdx.x * 256 + threadIdx.x;
    if (u >= 4338) return;
    float v = 0.f;
    if (u < 2016) {
        const int t = u / 224, c = u % 224;
        if (c < 64)       v = dw0[t*209 + 81  + c];
        else if (c < 128) v = dw0[t*209 + 145 + (c-64)];
        else if (c < 209) v = dw0[t*209 + (c-128)];
    } else if (u < 3168) {
        const int r = u-2016, t = r/128, c = r%128; v = dw1[t*128+c];
    } else if (u < 3744) {
        const int r = u-3168, t = r/64, c = r%64; v = dw2[t*64+c];
    } else if (u < 4032) {
        const int r = u-3744, t = r/32, c = r%32; v = dw3[t*32+c];
    } else if (u < 4320) {              // fwp[t][c][s] = sc[c]*fw[t][c][s]
        const int r = u-4032, t = r/32, rem = r%32, c = rem >> 1, s = rem & 1;
        const float sc = bn_g[c] * rsqrtf(bn_v[c] + 1e-3f);
        v = sc * fw[t*32 + c*2 + s];
    } else {                            // tb[t][s] = sum_c sh[c]*fw[t][c][s]
        const int r = u-4320, t = r/2, s = r%2;
        float a = 0.f;
        for (int c = 0; c < 16; ++c) {
            const float sc = bn_g[c] * rsqrtf(bn_v[c] + 1e-3f);
            const float sh = bn_b[c] - bn_m[c] * sc;
            a += sh * fw[t*32 + c*2 + s];
        }
        v = a;
    }
    fout[u] = v;
}

// ---------------------------------------------------------------------------
// Cost volume v3: MFMA banded QK^T, 32x4 tile, double-buffered sNxt with
// register prefetch. v3 change: prv section of xout is written directly from
// the af0/af1 bf16 fragments (jt==0 waves) in the prologue, eliminating the
// epilogue's 75.5 MB f32 re-read of prv. Traffic now = 151 MB read +
// 131.5 MB write = the single-pass minimum.
// ---------------------------------------------------------------------------
template<int UNIFIED>
__global__ __launch_bounds__(256) void cost_mfma_kernel(
    const float* __restrict__ prv, const float* __restrict__ nxt,
    __hip_bfloat16* __restrict__ xout)
{
    constexpr int OST   = UNIFIED ? 224 : CVP;
    constexpr int CVOFF = UNIFIED ? 128 : 0;

    __shared__ __align__(16) short sNxt[2][48][70];
    __shared__ __align__(16) short sCv[4][32][96];

    const int tid  = threadIdx.x;
    const int lane = tid & 63;
    const int wv   = tid >> 6;
    const int ln15 = lane & 15;
    const int kq   = lane >> 4;
    const int mt   = wv & 1;
    const int jt   = wv >> 1;

    const int bx = blockIdx.x;
    const int tw = bx % 6;
    const int th = (bx / 6) % 48;
    const int b  = bx / 288;
    const int w0 = tw * 32, h0 = th * 4;

    {
        const short8 z = {0,0,0,0,0,0,0,0};
#pragma unroll
        for (int t = 0; t < 6; ++t) {
            const int idx = tid + t * 256;
            const int row = idx / 384, rem = idx % 384;
            const int px = rem / 12, c8 = rem % 12;
            *(short8*)&sCv[row][px][c8 * 8] = z;
        }
    }

    short8 af0[4], af1[4];
    {
        const int apx = w0 + mt * 16 + ln15;
#pragma unroll
        for (int r4 = 0; r4 < 4; ++r4) {
            const float* ap = prv + (((size_t)b * HH + h0 + r4) * WW + apx) * CC0 + kq * 8;
            const float4 x0 = *(const float4*)(ap);
            const float4 x1 = *(const float4*)(ap + 4);
            const float4 x2 = *(const float4*)(ap + 32);
            const float4 x3 = *(const float4*)(ap + 36);
            af0[r4][0]=f2bf(x0.x); af0[r4][1]=f2bf(x0.y); af0[r4][2]=f2bf(x0.z); af0[r4][3]=f2bf(x0.w);
            af0[r4][4]=f2bf(x1.x); af0[r4][5]=f2bf(x1.y); af0[r4][6]=f2bf(x1.z); af0[r4][7]=f2bf(x1.w);
            af1[r4][0]=f2bf(x2.x); af1[r4][1]=f2bf(x2.y); af1[r4][2]=f2bf(x2.z); af1[r4][3]=f2bf(x2.w);
            af1[r4][4]=f2bf(x3.x); af1[r4][5]=f2bf(x3.y); af1[r4][6]=f2bf(x3.z); af1[r4][7]=f2bf(x3.w);
        }
    }

    // v3: prv section of xout written from the fragments (jt==0 waves cover
    // all 32 px x 64 ch x 4 rows; values bit-identical to f2bf(prv f32)).
    if (UNIFIED && jt == 0) {
#pragma unroll
        for (int r4 = 0; r4 < 4; ++r4) {
            short* op = (short*)xout
                + (((size_t)b * HH + h0 + r4) * WW + w0 + mt * 16 + ln15) * OST
                + kq * 8;
            *(short8*)op = af0[r4];
            *(short8*)(op + 32) = af1[r4];
        }
    }

    int cur = 0;
    {
        const int y0 = h0 - 4;
        if ((unsigned)y0 < (unsigned)HH) {
            const float* rowp = nxt + (((size_t)b * HH + y0) * WW) * CC0;
#pragma unroll
            for (int t = 0; t < 3; ++t) {
                const int u = tid + t * 256;
                if (u < 640) {
                    const int px = u >> 4, c4 = u & 15;
                    const int gw = w0 - 4 + px;
                    float4 v = make_float4(0.f, 0.f, 0.f, 0.f);
                    if ((unsigned)gw < (unsigned)WW)
                        v = *(const float4*)(rowp + (size_t)gw * CC0 + c4 * 4);
                    short4v sv;
                    sv[0]=f2bf(v.x); sv[1]=f2bf(v.y); sv[2]=f2bf(v.z); sv[3]=f2bf(v.w);
                    *(short4v*)&sNxt[0][px][c4 * 4] = sv;
                }
            }
        }
    }

    const size_t obase_blk = (((size_t)b * HH + h0) * WW + w0);

    for (int i = 0; i < 12; ++i) {
        const int y = h0 - 4 + i;
        const bool yok = ((unsigned)y < (unsigned)HH);
        __syncthreads();

        const int yn = y + 1;
        const bool nok = (i < 11) && ((unsigned)yn < (unsigned)HH);
        float4 sreg[3];
        if (nok) {
            const float* rowp = nxt + (((size_t)b * HH + yn) * WW) * CC0;
#pragma unroll
            for (int t = 0; t < 3; ++t) {
                const int u = tid + t * 256;
                sreg[t] = make_float4(0.f, 0.f, 0.f, 0.f);
                if (u < 640) {
                    const int px = u >> 4, c4 = u & 15;
                    const int gw = w0 - 4 + px;
                    if ((unsigned)gw < (unsigned)WW)
                        sreg[t] = *(const float4*)(rowp + (size_t)gw * CC0 + c4 * 4);
                }
            }
        }

        if (yok) {
            const int nb = mt * 16 + jt * 16 + ln15;
            const short* bp = &sNxt[cur][nb][kq * 8];
            const short8 b0 = *(const short8*)bp;
            const short8 b1 = *(const short8*)(bp + 32);
#pragma unroll
            for (int r4 = 0; r4 < 4; ++r4) {
                const int h = h0 + r4;
                const int rband = y - h + 4;
                if ((unsigned)rband <= 8u) {
                    f32x4 acc = {0.f, 0.f, 0.f, 0.f};
                    acc = __builtin_amdgcn_mfma_f32_16x16x32_bf16(af0[r4], b0, acc, 0, 0, 0);
                    acc = __builtin_amdgcn_mfma_f32_16x16x32_bf16(af1[r4], b1, acc, 0, 0, 0);
#pragma unroll
                    for (int rr = 0; rr < 4; ++rr) {
                        const int m_local = kq * 4 + rr;
                        const int dj = jt * 16 + ln15 - m_local;
                        if ((unsigned)dj < 9u) {
                            float mv = acc[rr] * (1.0f / 64.0f);
                            mv = (mv > 0.f) ? mv : 0.1f * mv;
                            sCv[r4][mt * 16 + m_local][rband * 9 + dj] = f2bf(mv);
                        }
                    }
                }
            }
            if (UNIFIED && y >= h0 && y < h0 + 4) {
                const int px_o = tid >> 3, cg = tid & 7;
                short* op = (short*)xout + (((size_t)b * HH + y) * WW + w0 + px_o) * OST
                            + 64 + cg * 8;
                *(short8*)op = *(const short8*)&sNxt[cur][4 + px_o][cg * 8];
            }
        }

        if (nok) {
#pragma unroll
            for (int t = 0; t < 3; ++t) {
                const int u = tid + t * 256;
                if (u < 640) {
                    const int px = u >> 4, c4 = u & 15;
                    short4v sv;
                    sv[0]=f2bf(sreg[t].x); sv[1]=f2bf(sreg[t].y);
                    sv[2]=f2bf(sreg[t].z); sv[3]=f2bf(sreg[t].w);
                    *(short4v*)&sNxt[cur ^ 1][px][c4 * 4] = sv;
                }
            }
        }
        cur ^= 1;
    }

    __syncthreads();
#pragma unroll
    for (int t = 0; t < 6; ++t) {
        const int idx = tid + t * 256;
        const int row = idx / 384, rem = idx % 384;
        const int px = rem / 12, c8 = rem % 12;
        short* op = (short*)xout + (obase_blk + (size_t)row * WW + px) * OST + CVOFF + c8 * 8;
        *(short8*)op = *(const short8*)&sCv[row][px][c8 * 8];
    }
    // v3: epilogue prv copy removed (handled from af fragments in prologue)
}

// ---------------------------------------------------------------------------
// Fused sepconv v2: SOFTWARE-PIPELINED.
// Per chunk: write prefetched regs -> sIn, barrier, ISSUE next chunk's global
// loads (regs) + this chunk's B-frag loads (L2-hot Bt, no LDS staging),
// dw compute -> sA, barrier, MFMA. Global latency hidden behind dw+MFMA.
// Single-buffered LDS is race-free: sIn writes happen only after barrier2 of
// the previous chunk; sA overwrites only after barrier1 (implied waitcnt has
// drained the previous MFMA's frag ds_reads).
// ---------------------------------------------------------------------------
template<int KP, int COUT, int MODE>
__global__ __launch_bounds__(256) void sepconv_mfma(
    const __hip_bfloat16* __restrict__ in,
    const float* __restrict__ prv, const float* __restrict__ nxt,
    const float* __restrict__ dwf,             // [9][KP] f32
    const __hip_bfloat16* __restrict__ Bt,     // [COUT][KP]
    const float* __restrict__ bias,
    __hip_bfloat16* __restrict__ out)
{
    constexpr int NC  = KP / 32;
    constexpr int NT  = COUT / 16;
    constexpr int WGN = (NT >= 2) ? 2 : 1;
    constexpr int WGM = 4 / WGN;
    constexpr int TM  = 8 / WGM;
    constexpr int TN  = NT / WGN;

    __shared__ __align__(16) short sIn[6][34][32];   // 13056 B
    __shared__ __align__(16) short sA[4][128][8];    //  8192 B

    const int tid  = threadIdx.x;
    const int lane = tid & 63;
    const int wv   = tid >> 6;
    const int ln15 = lane & 15;
    const int kq   = lane >> 4;
    const int wm   = wv % WGM;
    const int wn   = wv / WGM;

    const int bx = blockIdx.x;
    const int tw = bx % 6;
    const int th = (bx / 6) % 48;
    const int bb = bx / 288;
    const int w0 = tw * 32, h0 = th * 4;

    // depthwise mapping: wave-uniform k-slice (SGPR weights), lane = px
    const int dkbu = __builtin_amdgcn_readfirstlane(wv);
    const int dww  = lane & 31;
    const int dhh  = (lane >> 5) * 2;

    // staging-unit loader: unit u in [0,816) = (px p=u>>2, kblock kb=u&3)
    auto load_unit = [&](int u, int k0) -> short8 {
        const int kb = u & 3;
        const int p  = u >> 2;
        const int iw = p % 34, ih = p / 34;
        const int gw = w0 - 1 + iw, gh = h0 - 1 + ih;
        short8 v = {0,0,0,0,0,0,0,0};
        if ((unsigned)gw < (unsigned)WW && (unsigned)gh < (unsigned)HH) {
            const size_t pix = ((size_t)bb * HH + gh) * WW + gw;
            const int c0 = k0 + kb * 8;
            if (MODE == 0) {
                v = *(const short8*)((const short*)in + pix * KP + c0);
            } else {
                if (c0 < 64) {
                    const float4* s = (const float4*)(prv + pix * 64 + c0);
                    const float4 a = s[0], bq = s[1];
                    v[0]=f2bf(a.x);  v[1]=f2bf(a.y);  v[2]=f2bf(a.z);  v[3]=f2bf(a.w);
                    v[4]=f2bf(bq.x); v[5]=f2bf(bq.y); v[6]=f2bf(bq.z); v[7]=f2bf(bq.w);
                } else if (c0 < 128) {
                    const float4* s = (const float4*)(nxt + pix * 64 + (c0 - 64));
                    const float4 a = s[0], bq = s[1];
                    v[0]=f2bf(a.x);  v[1]=f2bf(a.y);  v[2]=f2bf(a.z);  v[3]=f2bf(a.w);
                    v[4]=f2bf(bq.x); v[5]=f2bf(bq.y); v[6]=f2bf(bq.z); v[7]=f2bf(bq.w);
                } else {
                    v = *(const short8*)((const short*)in + pix * CVP + (c0 - 128));
                }
            }
        }
        return v;
    };

    f32x4 acc[TM][TN] = {};
    short8 pr[4];

    // prologue: prefetch chunk 0
#pragma unroll
    for (int t = 0; t < 4; ++t) {
        const int u = tid + t * 256;
        pr[t] = (u < 816) ? load_unit(u, 0) : short8{0,0,0,0,0,0,0,0};
    }

#pragma unroll
    for (int c = 0; c < NC; ++c) {
        const int k0 = c * 32;
        // --- commit prefetched staging to LDS (flat offset = u*16B) ---
#pragma unroll
        for (int t = 0; t < 4; ++t) {
            const int u = tid + t * 256;
            if (u < 816) *(short8*)((short*)sIn + (size_t)u * 8) = pr[t];
        }
        __syncthreads();

        // --- issue next chunk's global loads (hidden behind dw+MFMA) ---
        if (c + 1 < NC) {
#pragma unroll
            for (int t = 0; t < 4; ++t) {
                const int u = tid + t * 256;
                if (u < 816) pr[t] = load_unit(u, k0 + 32);
            }
        }
        // --- B-frags direct from global (Bt is L2-resident) ---
        short8 bfr[TN];
#pragma unroll
        for (int j = 0; j < TN; ++j) {
            const int n = (wn * TN + j) * 16 + ln15;
            bfr[j] = *(const short8*)((const short*)Bt + (size_t)n * KP + k0 + kq * 8);
        }

        // --- depthwise: 2 vertically-adjacent px, 8 ch; f32 SGPR weights ---
        {
            const float* wrow = dwf + k0 + dkbu * 8;
            float r0[8] = {0,0,0,0,0,0,0,0};
            float r1[8] = {0,0,0,0,0,0,0,0};
#pragma unroll
            for (int dy = 0; dy < 4; ++dy) {
#pragma unroll
                for (int dx = 0; dx < 3; ++dx) {
                    const short8 iv = *(const short8*)&sIn[dhh + dy][dww + dx][dkbu * 8];
                    float fv[8];
                    cvt8(iv, fv);
                    if (dy < 3) {
#pragma unroll
                        for (int j = 0; j < 8; ++j)
                            r0[j] += fv[j] * wrow[(dy * 3 + dx) * KP + j];
                    }
                    if (dy >= 1) {
#pragma unroll
                        for (int j = 0; j < 8; ++j)
                            r1[j] += fv[j] * wrow[((dy - 1) * 3 + dx) * KP + j];
                    }
                }
            }
            const int px0 = dhh * 32 + dww;
            short8 o0, o1;
#pragma unroll
            for (int j = 0; j < 8; ++j) { o0[j] = f2bf(r0[j]); o1[j] = f2bf(r1[j]); }
            *(short8*)&sA[dkbu][px0 ^ (dkbu << 2)][0] = o0;
            *(short8*)&sA[dkbu][(px0 + 32) ^ (dkbu << 2)][0] = o1;
        }
        __syncthreads();

        // --- MFMA ---
        short8 af[TM];
#pragma unroll
        for (int i = 0; i < TM; ++i) {
            const int m = (wm * TM + i) * 16 + ln15;
            af[i] = *(const short8*)&sA[kq][m ^ (kq << 2)][0];
        }
#pragma unroll
        for (int i = 0; i < TM; ++i)
#pragma unroll
            for (int j = 0; j < TN; ++j)
                acc[i][j] = __builtin_amdgcn_mfma_f32_16x16x32_bf16(
                    af[i], bfr[j], acc[i][j], 0, 0, 0);
    }

#pragma unroll
    for (int j = 0; j < TN; ++j) {
        const int n = (wn * TN + j) * 16 + ln15;
        const float bj = bias[n];
#pragma unroll
        for (int i = 0; i < TM; ++i) {
#pragma unroll
            for (int r = 0; r < 4; ++r) {
                const int m  = (wm * TM + i) * 16 + kq * 4 + r;
                const int gh = h0 + (m >> 5), gw = w0 + (m & 31);
                const size_t gp = ((size_t)bb * HH + gh) * WW + gw;
                out[gp * COUT + n] = __float2bfloat16(mish_f(acc[i][j][r] + bj));
            }
        }
    }
}

// ---------------------------------------------------------------------------
// BN folded into flow conv: out = SC * sum_{taps in-bounds} (tb[t] + x.fwp[t])
// ---------------------------------------------------------------------------
__global__ __launch_bounds__(256) void bn_flow_kernel(
    const __hip_bfloat16* __restrict__ xin,
    const float* __restrict__ fwp, const float* __restrict__ tbv,
    float* __restrict__ out)
{
    const int pix = blockIdx.x * 256 + threadIdx.x;
    const int wq  = pix % WW;
    const int hq  = (pix / WW) % HH;
    const int bq  = pix / (WW * HH);
    float a0 = 0.f, a1 = 0.f;
#pragma unroll
    for (int dy = -1; dy <= 1; ++dy) {
        const int yy = hq + dy;
        if ((unsigned)yy >= HH) continue;
#pragma unroll
        for (int dx = -1; dx <= 1; ++dx) {
            const int xx = wq + dx;
            if ((unsigned)xx >= WW) continue;
            const int t = (dy + 1) * 3 + (dx + 1);
            a0 += tbv[t * 2 + 0];
            a1 += tbv[t * 2 + 1];
            const short* xp = (const short*)xin + (((size_t)bq * HH + yy) * WW + xx) * 16;
            const short8 v0 = *(const short8*)xp;
            const short8 v1 = *(const short8*)(xp + 8);
            float x[16];
            cvt8(v0, x); cvt8(v1, x + 8);
            const float* wp = fwp + t * 32;
#pragma unroll
            for (int c = 0; c < 16; ++c) {
                a0 += x[c] * wp[c * 2 + 0];
                a1 += x[c] * wp[c * 2 + 1];
            }
        }
    }
    const float SC = sqrtf((float)(HH * HH + WW * WW));
    out[(size_t)pix * 2 + 0] = SC * a0;
    out[(size_t)pix * 2 + 1] = SC * a1;
}

// ---------------------------------------------------------------------------
// Workspace:
// UNIFIED (ws >= ~208 MB): x0b[N][224] | t1[N][128] | wts bf16 | f32 wts
// FALLBACK (ws >= ~133 MB): cv[N][96]  | t1[N][128] | wts bf16 | f32 wts
// t2 = ws[0:N*64], t3 = t1, t4 = ws[N*64:N*80] in both.
// ---------------------------------------------------------------------------
extern "C" void kernel_launch(void* const* d_in, const int* in_sizes, int n_in,
                              void* d_out, int out_size, void* d_ws, size_t ws_size,
                              hipStream_t stream)
{
    const float* prv   = (const float*)d_in[0];
    const float* nxt   = (const float*)d_in[1];
    const float* dw0   = (const float*)d_in[2];
    const float* pw0   = (const float*)d_in[3];
    const float* b0    = (const float*)d_in[4];
    const float* dw1   = (const float*)d_in[5];
    const float* pw1   = (const float*)d_in[6];
    const float* b1    = (const float*)d_in[7];
    const float* dw2   = (const float*)d_in[8];
    const float* pw2   = (const float*)d_in[9];
    const float* b2    = (const float*)d_in[10];
    const float* dw3   = (const float*)d_in[11];
    const float* pw3   = (const float*)d_in[12];
    const float* b3    = (const float*)d_in[13];
    const float* bn_g  = (const float*)d_in[14];
    const float* bn_b  = (const float*)d_in[15];
    const float* bn_m  = (const float*)d_in[16];
    const float* bn_v  = (const float*)d_in[17];
    const float* fw    = (const float*)d_in[18];
    float* outp = (float*)d_out;

    const size_t N = (size_t)NPIX;
    __hip_bfloat16* ws = (__hip_bfloat16*)d_ws;

    const size_t need_uni = (N * 352 + 43456) * 2 + 4338 * 4;
    const bool uni = (ws_size >= need_uni);

    __hip_bfloat16* t1  = uni ? (ws + N * 224) : (ws + N * 96);
    __hip_bfloat16* wts = uni ? (ws + N * 352) : (ws + N * 224);
    __hip_bfloat16* t2  = ws;                    // aliases x0b/cv (dead then)
    __hip_bfloat16* t3  = t1;
    __hip_bfloat16* t4  = ws + N * 64;
    __hip_bfloat16* Bt0 = wts + 4032;
    __hip_bfloat16* Bt1 = wts + 32704;
    __hip_bfloat16* Bt2 = wts + 40896;
    __hip_bfloat16* Bt3 = wts + 42944;
    float* fwt = (float*)(wts + 43456);          // dwf0|dwf1|dwf2|dwf3|fwp|tb

    prep_kernel<<<170, 256, 0, stream>>>(dw0, pw0, dw1, pw1, dw2, pw2, dw3, pw3, wts);
    prep2_kernel<<<17, 256, 0, stream>>>(dw0, dw1, dw2, dw3,
                                         bn_g, bn_b, bn_m, bn_v, fw, fwt);
    if (uni) {
        cost_mfma_kernel<1><<<2304, 256, 0, stream>>>(prv, nxt, ws);
        sepconv_mfma<224, 128, 0><<<2304, 256, 0, stream>>>(ws, nullptr, nullptr,
                                                            fwt, Bt0, b0, t1);
    } else {
        cost_mfma_kernel<0><<<2304, 256, 0, stream>>>(prv, nxt, ws);
        sepconv_mfma<224, 128, 1><<<2304, 256, 0, stream>>>(ws, prv, nxt,
                                                            fwt, Bt0, b0, t1);
    }
    sepconv_mfma<128, 64, 0><<<2304, 256, 0, stream>>>(t1, nullptr, nullptr,
                                                       fwt + 2016, Bt1, b1, t2);
    sepconv_mfma<64, 32, 0><<<2304, 256, 0, stream>>>(t2, nullptr, nullptr,
                                                      fwt + 3168, Bt2, b2, t3);
    sepconv_mfma<32, 16, 0><<<2304, 256, 0, stream>>>(t3, nullptr, nullptr,
                                                      fwt + 3744, Bt3, b3, t4);
    bn_flow_kernel<<<NPIX / 256, 256, 0, stream>>>(t4, fwt + 4032, fwt + 4320, outp);
}

// Round 2
// 466.720 us; speedup vs baseline: 1.1173x; 1.1173x over previous
//
#include <hip/hip_runtime.h>
#include <hip/hip_bf16.h>

// Problem constants
#define BB 8
#define HH 192
#define WW 192
#define CC0 64
#define NPIX (BB*HH*WW) // 294912
#define NCV 81
#define CVP 96          // cv padded channels in fallback layout

typedef __attribute__((ext_vector_type(8))) short short8;
typedef __attribute__((ext_vector_type(4))) short short4v;
typedef __attribute__((ext_vector_type(4))) float f32x4;

__device__ __forceinline__ float bf2f(short s) {
    union { unsigned u; float f; } x; x.u = ((unsigned)(unsigned short)s) << 16; return x.f;
}
__device__ __forceinline__ short f2bf(float f) {
    __hip_bfloat16 h = __float2bfloat16(f);
    return *reinterpret_cast<short*>(&h);
}
__device__ __forceinline__ void cvt8(const short8 iv, float* fv) {
    const int* ip = (const int*)&iv;
#pragma unroll
    for (int e = 0; e < 4; ++e) {
        union { unsigned u; float f; } lo, hi;
        lo.u = ((unsigned)ip[e]) << 16;
        hi.u = ((unsigned)ip[e]) & 0xffff0000u;
        fv[2 * e] = lo.f; fv[2 * e + 1] = hi.f;
    }
}

__device__ __forceinline__ float mish_f(float v) {
    if (v > 20.0f) return v;
    const float u = __expf(v);
    const float n = u * (u + 2.0f);
    return v * n / (n + 2.0f);
}

// ---------------------------------------------------------------------------
// Weight prep (bf16 Bt matrices, channel order [prv|nxt|cv|pad]) — as R4.
// ---------------------------------------------------------------------------
__global__ __launch_bounds__(256) void prep_kernel(
    const float* __restrict__ dw0, const float* __restrict__ pw0,
    const float* __restrict__ dw1, const float* __restrict__ pw1,
    const float* __restrict__ dw2, const float* __restrict__ pw2,
    const float* __restrict__ dw3, const float* __restrict__ pw3,
    __hip_bfloat16* __restrict__ wout)
{
    const int u = blockIdx.x * 256 + threadIdx.x;
    if (u >= 43456) return;
    float v = 0.f;
    if (u < 2016) {                     // legacy dwbf0 slot (unused, kept for layout)
        const int t = u / 224, c = u % 224;
        if (c < 64)       v = dw0[t*209 + 81  + c];
        else if (c < 128) v = dw0[t*209 + 145 + (c-64)];
        else if (c < 209) v = dw0[t*209 + (c-128)];
    } else if (u < 3168) {
        const int r = u-2016, t = r/128, c = r%128; v = dw1[t*128+c];
    } else if (u < 3744) {
        const int r = u-3168, t = r/64, c = r%64; v = dw2[t*64+c];
    } else if (u < 4032) {
        const int r = u-3744, t = r/32, c = r%32; v = dw3[t*32+c];
    } else if (u < 32704) {             // Bt0 [128][224]
        const int r = u-4032, n = r/224, c = r%224;
        if (c < 64)       v = pw0[(81+c)*128 + n];
        else if (c < 128) v = pw0[(145+(c-64))*128 + n];
        else if (c < 209) v = pw0[(c-128)*128 + n];
    } else if (u < 40896) {             // Bt1 [64][128]
        const int r = u-32704, n = r/128, c = r%128; v = pw1[c*64 + n];
    } else if (u < 42944) {             // Bt2 [32][64]
        const int r = u-40896, n = r/64, c = r%64; v = pw2[c*32 + n];
    } else {                            // Bt3 [16][32]
        const int r = u-42944, n = r/32, c = r%32; v = pw3[c*16 + n];
    }
    wout[u] = __float2bfloat16(v);
}

// ---------------------------------------------------------------------------
// prep2: f32 dw weights (stage0 permuted to [prv|nxt|cv|pad]) + fused BN*flow
// weights. fout: dwf0[2016] dwf1[1152] dwf2[576] dwf3[288] fwp[288] tb[18]
// ---------------------------------------------------------------------------
__global__ __launch_bounds__(256) void prep2_kernel(
    const float* __restrict__ dw0, const float* __restrict__ dw1,
    const float* __restrict__ dw2, const float* __restrict__ dw3,
    const float* __restrict__ bn_g, const float* __restrict__ bn_b,
    const float* __restrict__ bn_m, const float* __restrict__ bn_v,
    const float* __restrict__ fw, float* __restrict__ fout)
{
    const int u = blockIdx.x * 256 + threadIdx.x;
    if (u >= 4338) return;
    float v = 0.f;
    if (u < 2016) {
        const int t = u / 224, c = u % 224;
        if (c < 64)       v = dw0[t*209 + 81  + c];
        else if (c < 128) v = dw0[t*209 + 145 + (c-64)];
        else if (c < 209) v = dw0[t*209 + (c-128)];
    } else if (u < 3168) {
        const int r = u-2016, t = r/128, c = r%128; v = dw1[t*128+c];
    } else if (u < 3744) {
        const int r = u-3168, t = r/64, c = r%64; v = dw2[t*64+c];
    } else if (u < 4032) {
        const int r = u-3744, t = r/32, c = r%32; v = dw3[t*32+c];
    } else if (u < 4320) {              // fwp[t][c][s] = sc[c]*fw[t][c][s]
        const int r = u-4032, t = r/32, rem = r%32, c = rem >> 1, s = rem & 1;
        const float sc = bn_g[c] * rsqrtf(bn_v[c] + 1e-3f);
        v = sc * fw[t*32 + c*2 + s];
    } else {                            // tb[t][s] = sum_c sh[c]*fw[t][c][s]
        const int r = u-4320, t = r/2, s = r%2;
        float a = 0.f;
        for (int c = 0; c < 16; ++c) {
            const float sc = bn_g[c] * rsqrtf(bn_v[c] + 1e-3f);
            const float sh = bn_b[c] - bn_m[c] * sc;
            a += sh * fw[t*32 + c*2 + s];
        }
        v = a;
    }
    fout[u] = v;
}

// ---------------------------------------------------------------------------
// Cost volume v3: MFMA banded QK^T, 32x4 tile, double-buffered sNxt with
// register prefetch. prv section of xout is written directly from the
// af0/af1 bf16 fragments (jt==0 waves) in the prologue (no epilogue re-read).
// ---------------------------------------------------------------------------
template<int UNIFIED>
__global__ __launch_bounds__(256) void cost_mfma_kernel(
    const float* __restrict__ prv, const float* __restrict__ nxt,
    __hip_bfloat16* __restrict__ xout)
{
    constexpr int OST   = UNIFIED ? 224 : CVP;
    constexpr int CVOFF = UNIFIED ? 128 : 0;

    __shared__ __align__(16) short sNxt[2][48][70];
    __shared__ __align__(16) short sCv[4][32][96];

    const int tid  = threadIdx.x;
    const int lane = tid & 63;
    const int wv   = tid >> 6;
    const int ln15 = lane & 15;
    const int kq   = lane >> 4;
    const int mt   = wv & 1;
    const int jt   = wv >> 1;

    const int bx = blockIdx.x;
    const int tw = bx % 6;
    const int th = (bx / 6) % 48;
    const int b  = bx / 288;
    const int w0 = tw * 32, h0 = th * 4;

    {
        const short8 z = {0,0,0,0,0,0,0,0};
#pragma unroll
        for (int t = 0; t < 6; ++t) {
            const int idx = tid + t * 256;
            const int row = idx / 384, rem = idx % 384;
            const int px = rem / 12, c8 = rem % 12;
            *(short8*)&sCv[row][px][c8 * 8] = z;
        }
    }

    short8 af0[4], af1[4];
    {
        const int apx = w0 + mt * 16 + ln15;
#pragma unroll
        for (int r4 = 0; r4 < 4; ++r4) {
            const float* ap = prv + (((size_t)b * HH + h0 + r4) * WW + apx) * CC0 + kq * 8;
            const float4 x0 = *(const float4*)(ap);
            const float4 x1 = *(const float4*)(ap + 4);
            const float4 x2 = *(const float4*)(ap + 32);
            const float4 x3 = *(const float4*)(ap + 36);
            af0[r4][0]=f2bf(x0.x); af0[r4][1]=f2bf(x0.y); af0[r4][2]=f2bf(x0.z); af0[r4][3]=f2bf(x0.w);
            af0[r4][4]=f2bf(x1.x); af0[r4][5]=f2bf(x1.y); af0[r4][6]=f2bf(x1.z); af0[r4][7]=f2bf(x1.w);
            af1[r4][0]=f2bf(x2.x); af1[r4][1]=f2bf(x2.y); af1[r4][2]=f2bf(x2.z); af1[r4][3]=f2bf(x2.w);
            af1[r4][4]=f2bf(x3.x); af1[r4][5]=f2bf(x3.y); af1[r4][6]=f2bf(x3.z); af1[r4][7]=f2bf(x3.w);
        }
    }

    // prv section of xout written from the fragments (jt==0 waves cover
    // all 32 px x 64 ch x 4 rows; values bit-identical to f2bf(prv f32)).
    if (UNIFIED && jt == 0) {
#pragma unroll
        for (int r4 = 0; r4 < 4; ++r4) {
            short* op = (short*)xout
                + (((size_t)b * HH + h0 + r4) * WW + w0 + mt * 16 + ln15) * OST
                + kq * 8;
            *(short8*)op = af0[r4];
            *(short8*)(op + 32) = af1[r4];
        }
    }

    int cur = 0;
    {
        const int y0 = h0 - 4;
        if ((unsigned)y0 < (unsigned)HH) {
            const float* rowp = nxt + (((size_t)b * HH + y0) * WW) * CC0;
#pragma unroll
            for (int t = 0; t < 3; ++t) {
                const int u = tid + t * 256;
                if (u < 640) {
                    const int px = u >> 4, c4 = u & 15;
                    const int gw = w0 - 4 + px;
                    float4 v = make_float4(0.f, 0.f, 0.f, 0.f);
                    if ((unsigned)gw < (unsigned)WW)
                        v = *(const float4*)(rowp + (size_t)gw * CC0 + c4 * 4);
                    short4v sv;
                    sv[0]=f2bf(v.x); sv[1]=f2bf(v.y); sv[2]=f2bf(v.z); sv[3]=f2bf(v.w);
                    *(short4v*)&sNxt[0][px][c4 * 4] = sv;
                }
            }
        }
    }

    const size_t obase_blk = (((size_t)b * HH + h0) * WW + w0);

    for (int i = 0; i < 12; ++i) {
        const int y = h0 - 4 + i;
        const bool yok = ((unsigned)y < (unsigned)HH);
        __syncthreads();

        const int yn = y + 1;
        const bool nok = (i < 11) && ((unsigned)yn < (unsigned)HH);
        float4 sreg[3];
        if (nok) {
            const float* rowp = nxt + (((size_t)b * HH + yn) * WW) * CC0;
#pragma unroll
            for (int t = 0; t < 3; ++t) {
                const int u = tid + t * 256;
                sreg[t] = make_float4(0.f, 0.f, 0.f, 0.f);
                if (u < 640) {
                    const int px = u >> 4, c4 = u & 15;
                    const int gw = w0 - 4 + px;
                    if ((unsigned)gw < (unsigned)WW)
                        sreg[t] = *(const float4*)(rowp + (size_t)gw * CC0 + c4 * 4);
                }
            }
        }

        if (yok) {
            const int nb = mt * 16 + jt * 16 + ln15;
            const short* bp = &sNxt[cur][nb][kq * 8];
            const short8 b0 = *(const short8*)bp;
            const short8 b1 = *(const short8*)(bp + 32);
#pragma unroll
            for (int r4 = 0; r4 < 4; ++r4) {
                const int h = h0 + r4;
                const int rband = y - h + 4;
                if ((unsigned)rband <= 8u) {
                    f32x4 acc = {0.f, 0.f, 0.f, 0.f};
                    acc = __builtin_amdgcn_mfma_f32_16x16x32_bf16(af0[r4], b0, acc, 0, 0, 0);
                    acc = __builtin_amdgcn_mfma_f32_16x16x32_bf16(af1[r4], b1, acc, 0, 0, 0);
#pragma unroll
                    for (int rr = 0; rr < 4; ++rr) {
                        const int m_local = kq * 4 + rr;
                        const int dj = jt * 16 + ln15 - m_local;
                        if ((unsigned)dj < 9u) {
                            float mv = acc[rr] * (1.0f / 64.0f);
                            mv = (mv > 0.f) ? mv : 0.1f * mv;
                            sCv[r4][mt * 16 + m_local][rband * 9 + dj] = f2bf(mv);
                        }
                    }
                }
            }
            if (UNIFIED && y >= h0 && y < h0 + 4) {
                const int px_o = tid >> 3, cg = tid & 7;
                short* op = (short*)xout + (((size_t)b * HH + y) * WW + w0 + px_o) * OST
                            + 64 + cg * 8;
                *(short8*)op = *(const short8*)&sNxt[cur][4 + px_o][cg * 8];
            }
        }

        if (nok) {
#pragma unroll
            for (int t = 0; t < 3; ++t) {
                const int u = tid + t * 256;
                if (u < 640) {
                    const int px = u >> 4, c4 = u & 15;
                    short4v sv;
                    sv[0]=f2bf(sreg[t].x); sv[1]=f2bf(sreg[t].y);
                    sv[2]=f2bf(sreg[t].z); sv[3]=f2bf(sreg[t].w);
                    *(short4v*)&sNxt[cur ^ 1][px][c4 * 4] = sv;
                }
            }
        }
        cur ^= 1;
    }

    __syncthreads();
#pragma unroll
    for (int t = 0; t < 6; ++t) {
        const int idx = tid + t * 256;
        const int row = idx / 384, rem = idx % 384;
        const int px = rem / 12, c8 = rem % 12;
        short* op = (short*)xout + (obase_blk + (size_t)row * WW + px) * OST + CVOFF + c8 * 8;
        *(short8*)op = *(const short8*)&sCv[row][px][c8 * 8];
    }
}

// ---------------------------------------------------------------------------
// Fused sepconv v3: software-pipelined as v2, plus:
//  (a) sIn is granule-XOR-swizzled: granule G(p,kb) = 4p + (kb ^ ((p>>1)&3)).
//      The depthwise read (kb wave-uniform, p per-lane) previously hit only
//      2 of 8 bank-groups -> ~4x LDS serialization (SQ_LDS_BANK_CONFLICT
//      1.03e7/dispatch). With the swizzle, 8 consecutive p cover all 8
//      bank-groups -> conflict-free ds_read_b128.
//  (b) staging address math (div/mod 34, bounds) hoisted out of the chunk
//      loop into precomputed pointers (MODE 0 path).
// ---------------------------------------------------------------------------
template<int KP, int COUT, int MODE>
__global__ __launch_bounds__(256) void sepconv_mfma(
    const __hip_bfloat16* __restrict__ in,
    const float* __restrict__ prv, const float* __restrict__ nxt,
    const float* __restrict__ dwf,             // [9][KP] f32
    const __hip_bfloat16* __restrict__ Bt,     // [COUT][KP]
    const float* __restrict__ bias,
    __hip_bfloat16* __restrict__ out)
{
    constexpr int NC  = KP / 32;
    constexpr int NT  = COUT / 16;
    constexpr int WGN = (NT >= 2) ? 2 : 1;
    constexpr int WGM = 4 / WGN;
    constexpr int TM  = 8 / WGM;
    constexpr int TN  = NT / WGN;

    __shared__ __align__(16) short sIn[816 * 8];     // 13056 B, granule-swizzled
    __shared__ __align__(16) short sA[4][128][8];    //  8192 B

    const int tid  = threadIdx.x;
    const int lane = tid & 63;
    const int wv   = tid >> 6;
    const int ln15 = lane & 15;
    const int kq   = lane >> 4;
    const int wm   = wv % WGM;
    const int wn   = wv / WGM;

    const int bx = blockIdx.x;
    const int tw = bx % 6;
    const int th = (bx / 6) % 48;
    const int bb = bx / 288;
    const int w0 = tw * 32, h0 = th * 4;

    // depthwise mapping: wave-uniform k-slice (SGPR weights), lane = px
    const int dkbu = __builtin_amdgcn_readfirstlane(wv);
    const int dww  = lane & 31;
    const int dhh  = (lane >> 5) * 2;

    // fallback-path loader (MODE 1 only): unit u = (px p=u>>2, kblock kb=u&3)
    auto load_unit = [&](int u, int k0) -> short8 {
        const int kb = u & 3;
        const int p  = u >> 2;
        const int iw = p % 34, ih = p / 34;
        const int gw = w0 - 1 + iw, gh = h0 - 1 + ih;
        short8 v = {0,0,0,0,0,0,0,0};
        if ((unsigned)gw < (unsigned)WW && (unsigned)gh < (unsigned)HH) {
            const size_t pix = ((size_t)bb * HH + gh) * WW + gw;
            const int c0 = k0 + kb * 8;
            if (c0 < 64) {
                const float4* s = (const float4*)(prv + pix * 64 + c0);
                const float4 a = s[0], bq = s[1];
                v[0]=f2bf(a.x);  v[1]=f2bf(a.y);  v[2]=f2bf(a.z);  v[3]=f2bf(a.w);
                v[4]=f2bf(bq.x); v[5]=f2bf(bq.y); v[6]=f2bf(bq.z); v[7]=f2bf(bq.w);
            } else if (c0 < 128) {
                const float4* s = (const float4*)(nxt + pix * 64 + (c0 - 64));
                const float4 a = s[0], bq = s[1];
                v[0]=f2bf(a.x);  v[1]=f2bf(a.y);  v[2]=f2bf(a.z);  v[3]=f2bf(a.w);
                v[4]=f2bf(bq.x); v[5]=f2bf(bq.y); v[6]=f2bf(bq.z); v[7]=f2bf(bq.w);
            } else {
                v = *(const short8*)((const short*)in + pix * CVP + (c0 - 128));
            }
        }
        return v;
    };

    // chunk-invariant staging sources (MODE 0 fast path)
    const short* sp[4];
    bool sok[4];
#pragma unroll
    for (int t = 0; t < 4; ++t) {
        const int u = tid + t * 256;
        const int kb = u & 3, p = u >> 2;
        const int iw = p % 34, ih = p / 34;
        const int gw = w0 - 1 + iw, gh = h0 - 1 + ih;
        sok[t] = (u < 816) && ((unsigned)gw < (unsigned)WW) && ((unsigned)gh < (unsigned)HH);
        const size_t pix = ((size_t)bb * HH + gh) * WW + gw;
        sp[t] = (const short*)in + pix * KP + kb * 8;
    }

    f32x4 acc[TM][TN] = {};
    short8 pr[4];

    // prologue: prefetch chunk 0
#pragma unroll
    for (int t = 0; t < 4; ++t) {
        pr[t] = short8{0,0,0,0,0,0,0,0};
        if (MODE == 0) {
            if (sok[t]) pr[t] = *(const short8*)(sp[t]);
        } else {
            const int u = tid + t * 256;
            if (u < 816) pr[t] = load_unit(u, 0);
        }
    }

#pragma unroll
    for (int c = 0; c < NC; ++c) {
        const int k0 = c * 32;
        // --- commit prefetched staging to LDS (granule-swizzled) ---
#pragma unroll
        for (int t = 0; t < 4; ++t) {
            const int u = tid + t * 256;
            if (u < 816) {
                const int ug = u ^ ((u >> 3) & 3);
                *(short8*)(sIn + (size_t)ug * 8) = pr[t];
            }
        }
        __syncthreads();

        // --- issue next chunk's global loads (hidden behind dw+MFMA) ---
        if (c + 1 < NC) {
#pragma unroll
            for (int t = 0; t < 4; ++t) {
                pr[t] = short8{0,0,0,0,0,0,0,0};
                if (MODE == 0) {
                    if (sok[t]) pr[t] = *(const short8*)(sp[t] + k0 + 32);
                } else {
                    const int u = tid + t * 256;
                    if (u < 816) pr[t] = load_unit(u, k0 + 32);
                }
            }
        }
        // --- B-frags direct from global (Bt is L2-resident) ---
        short8 bfr[TN];
#pragma unroll
        for (int j = 0; j < TN; ++j) {
            const int n = (wn * TN + j) * 16 + ln15;
            bfr[j] = *(const short8*)((const short*)Bt + (size_t)n * KP + k0 + kq * 8);
        }

        // --- depthwise: 2 vertically-adjacent px, 8 ch; f32 SGPR weights ---
        {
            const float* wrow = dwf + k0 + dkbu * 8;
            const int pbase = dhh * 34 + dww;
            float r0[8] = {0,0,0,0,0,0,0,0};
            float r1[8] = {0,0,0,0,0,0,0,0};
#pragma unroll
            for (int dy = 0; dy < 4; ++dy) {
#pragma unroll
                for (int dx = 0; dx < 3; ++dx) {
                    const int p2 = pbase + dy * 34 + dx;
                    const int g  = p2 * 4 + (dkbu ^ ((p2 >> 1) & 3));
                    const short8 iv = *(const short8*)(sIn + (size_t)g * 8);
                    float fv[8];
                    cvt8(iv, fv);
                    if (dy < 3) {
#pragma unroll
                        for (int j = 0; j < 8; ++j)
                            r0[j] += fv[j] * wrow[(dy * 3 + dx) * KP + j];
                    }
                    if (dy >= 1) {
#pragma unroll
                        for (int j = 0; j < 8; ++j)
                            r1[j] += fv[j] * wrow[((dy - 1) * 3 + dx) * KP + j];
                    }
                }
            }
            const int px0 = dhh * 32 + dww;
            short8 o0, o1;
#pragma unroll
            for (int j = 0; j < 8; ++j) { o0[j] = f2bf(r0[j]); o1[j] = f2bf(r1[j]); }
            *(short8*)&sA[dkbu][px0 ^ (dkbu << 2)][0] = o0;
            *(short8*)&sA[dkbu][(px0 + 32) ^ (dkbu << 2)][0] = o1;
        }
        __syncthreads();

        // --- MFMA ---
        short8 af[TM];
#pragma unroll
        for (int i = 0; i < TM; ++i) {
            const int m = (wm * TM + i) * 16 + ln15;
            af[i] = *(const short8*)&sA[kq][m ^ (kq << 2)][0];
        }
#pragma unroll
        for (int i = 0; i < TM; ++i)
#pragma unroll
            for (int j = 0; j < TN; ++j)
                acc[i][j] = __builtin_amdgcn_mfma_f32_16x16x32_bf16(
                    af[i], bfr[j], acc[i][j], 0, 0, 0);
    }

#pragma unroll
    for (int j = 0; j < TN; ++j) {
        const int n = (wn * TN + j) * 16 + ln15;
        const float bj = bias[n];
#pragma unroll
        for (int i = 0; i < TM; ++i) {
#pragma unroll
            for (int r = 0; r < 4; ++r) {
                const int m  = (wm * TM + i) * 16 + kq * 4 + r;
                const int gh = h0 + (m >> 5), gw = w0 + (m & 31);
                const size_t gp = ((size_t)bb * HH + gh) * WW + gw;
                out[gp * COUT + n] = __float2bfloat16(mish_f(acc[i][j][r] + bj));
            }
        }
    }
}

// ---------------------------------------------------------------------------
// BN folded into flow conv: out = SC * sum_{taps in-bounds} (tb[t] + x.fwp[t])
// ---------------------------------------------------------------------------
__global__ __launch_bounds__(256) void bn_flow_kernel(
    const __hip_bfloat16* __restrict__ xin,
    const float* __restrict__ fwp, const float* __restrict__ tbv,
    float* __restrict__ out)
{
    const int pix = blockIdx.x * 256 + threadIdx.x;
    const int wq  = pix % WW;
    const int hq  = (pix / WW) % HH;
    const int bq  = pix / (WW * HH);
    float a0 = 0.f, a1 = 0.f;
#pragma unroll
    for (int dy = -1; dy <= 1; ++dy) {
        const int yy = hq + dy;
        if ((unsigned)yy >= HH) continue;
#pragma unroll
        for (int dx = -1; dx <= 1; ++dx) {
            const int xx = wq + dx;
            if ((unsigned)xx >= WW) continue;
            const int t = (dy + 1) * 3 + (dx + 1);
            a0 += tbv[t * 2 + 0];
            a1 += tbv[t * 2 + 1];
            const short* xp = (const short*)xin + (((size_t)bq * HH + yy) * WW + xx) * 16;
            const short8 v0 = *(const short8*)xp;
            const short8 v1 = *(const short8*)(xp + 8);
            float x[16];
            cvt8(v0, x); cvt8(v1, x + 8);
            const float* wp = fwp + t * 32;
#pragma unroll
            for (int c = 0; c < 16; ++c) {
                a0 += x[c] * wp[c * 2 + 0];
                a1 += x[c] * wp[c * 2 + 1];
            }
        }
    }
    const float SC = sqrtf((float)(HH * HH + WW * WW));
    out[(size_t)pix * 2 + 0] = SC * a0;
    out[(size_t)pix * 2 + 1] = SC * a1;
}

// ---------------------------------------------------------------------------
// Workspace:
// UNIFIED (ws >= ~208 MB): x0b[N][224] | t1[N][128] | wts bf16 | f32 wts
// FALLBACK (ws >= ~133 MB): cv[N][96]  | t1[N][128] | wts bf16 | f32 wts
// t2 = ws[0:N*64], t3 = t1, t4 = ws[N*64:N*80] in both.
// ---------------------------------------------------------------------------
extern "C" void kernel_launch(void* const* d_in, const int* in_sizes, int n_in,
                              void* d_out, int out_size, void* d_ws, size_t ws_size,
                              hipStream_t stream)
{
    const float* prv   = (const float*)d_in[0];
    const float* nxt   = (const float*)d_in[1];
    const float* dw0   = (const float*)d_in[2];
    const float* pw0   = (const float*)d_in[3];
    const float* b0    = (const float*)d_in[4];
    const float* dw1   = (const float*)d_in[5];
    const float* pw1   = (const float*)d_in[6];
    const float* b1    = (const float*)d_in[7];
    const float* dw2   = (const float*)d_in[8];
    const float* pw2   = (const float*)d_in[9];
    const float* b2    = (const float*)d_in[10];
    const float* dw3   = (const float*)d_in[11];
    const float* pw3   = (const float*)d_in[12];
    const float* b3    = (const float*)d_in[13];
    const float* bn_g  = (const float*)d_in[14];
    const float* bn_b  = (const float*)d_in[15];
    const float* bn_m  = (const float*)d_in[16];
    const float* bn_v  = (const float*)d_in[17];
    const float* fw    = (const float*)d_in[18];
    float* outp = (float*)d_out;

    const size_t N = (size_t)NPIX;
    __hip_bfloat16* ws = (__hip_bfloat16*)d_ws;

    const size_t need_uni = (N * 352 + 43456) * 2 + 4338 * 4;
    const bool uni = (ws_size >= need_uni);

    __hip_bfloat16* t1  = uni ? (ws + N * 224) : (ws + N * 96);
    __hip_bfloat16* wts = uni ? (ws + N * 352) : (ws + N * 224);
    __hip_bfloat16* t2  = ws;                    // aliases x0b/cv (dead then)
    __hip_bfloat16* t3  = t1;
    __hip_bfloat16* t4  = ws + N * 64;
    __hip_bfloat16* Bt0 = wts + 4032;
    __hip_bfloat16* Bt1 = wts + 32704;
    __hip_bfloat16* Bt2 = wts + 40896;
    __hip_bfloat16* Bt3 = wts + 42944;
    float* fwt = (float*)(wts + 43456);          // dwf0|dwf1|dwf2|dwf3|fwp|tb

    prep_kernel<<<170, 256, 0, stream>>>(dw0, pw0, dw1, pw1, dw2, pw2, dw3, pw3, wts);
    prep2_kernel<<<17, 256, 0, stream>>>(dw0, dw1, dw2, dw3,
                                         bn_g, bn_b, bn_m, bn_v, fw, fwt);
    if (uni) {
        cost_mfma_kernel<1><<<2304, 256, 0, stream>>>(prv, nxt, ws);
        sepconv_mfma<224, 128, 0><<<2304, 256, 0, stream>>>(ws, nullptr, nullptr,
                                                            fwt, Bt0, b0, t1);
    } else {
        cost_mfma_kernel<0><<<2304, 256, 0, stream>>>(prv, nxt, ws);
        sepconv_mfma<224, 128, 1><<<2304, 256, 0, stream>>>(ws, prv, nxt,
                                                            fwt, Bt0, b0, t1);
    }
    sepconv_mfma<128, 64, 0><<<2304, 256, 0, stream>>>(t1, nullptr, nullptr,
                                                       fwt + 2016, Bt1, b1, t2);
    sepconv_mfma<64, 32, 0><<<2304, 256, 0, stream>>>(t2, nullptr, nullptr,
                                                      fwt + 3168, Bt2, b2, t3);
    sepconv_mfma<32, 16, 0><<<2304, 256, 0, stream>>>(t3, nullptr, nullptr,
                                                      fwt + 3744, Bt3, b3, t4);
    bn_flow_kernel<<<NPIX / 256, 256, 0, stream>>>(t4, fwt + 4032, fwt + 4320, outp);
}

// Round 3
// 453.063 us; speedup vs baseline: 1.1510x; 1.0301x over previous
//
#include <hip/hip_runtime.h>
#include <hip/hip_bf16.h>

// Problem constants
#define BB 8
#define HH 192
#define WW 192
#define CC0 64
#define NPIX (BB*HH*WW) // 294912
#define NCV 81
#define CVP 96          // cv padded channels in fallback layout

typedef __attribute__((ext_vector_type(8))) short short8;
typedef __attribute__((ext_vector_type(4))) short short4v;
typedef __attribute__((ext_vector_type(4))) float f32x4;

__device__ __forceinline__ float bf2f(short s) {
    union { unsigned u; float f; } x; x.u = ((unsigned)(unsigned short)s) << 16; return x.f;
}
__device__ __forceinline__ short f2bf(float f) {
    __hip_bfloat16 h = __float2bfloat16(f);
    return *reinterpret_cast<short*>(&h);
}
__device__ __forceinline__ void cvt8(const short8 iv, float* fv) {
    const int* ip = (const int*)&iv;
#pragma unroll
    for (int e = 0; e < 4; ++e) {
        union { unsigned u; float f; } lo, hi;
        lo.u = ((unsigned)ip[e]) << 16;
        hi.u = ((unsigned)ip[e]) & 0xffff0000u;
        fv[2 * e] = lo.f; fv[2 * e + 1] = hi.f;
    }
}

__device__ __forceinline__ float mish_f(float v) {
    if (v > 20.0f) return v;
    const float u = __expf(v);
    const float n = u * (u + 2.0f);
    return v * n / (n + 2.0f);
}

// ---------------------------------------------------------------------------
// Weight prep (bf16 Bt matrices, channel order [prv|nxt|cv|pad]) — as R4.
// ---------------------------------------------------------------------------
__global__ __launch_bounds__(256) void prep_kernel(
    const float* __restrict__ dw0, const float* __restrict__ pw0,
    const float* __restrict__ dw1, const float* __restrict__ pw1,
    const float* __restrict__ dw2, const float* __restrict__ pw2,
    const float* __restrict__ dw3, const float* __restrict__ pw3,
    __hip_bfloat16* __restrict__ wout)
{
    const int u = blockIdx.x * 256 + threadIdx.x;
    if (u >= 43456) return;
    float v = 0.f;
    if (u < 2016) {                     // legacy dwbf0 slot (unused, kept for layout)
        const int t = u / 224, c = u % 224;
        if (c < 64)       v = dw0[t*209 + 81  + c];
        else if (c < 128) v = dw0[t*209 + 145 + (c-64)];
        else if (c < 209) v = dw0[t*209 + (c-128)];
    } else if (u < 3168) {
        const int r = u-2016, t = r/128, c = r%128; v = dw1[t*128+c];
    } else if (u < 3744) {
        const int r = u-3168, t = r/64, c = r%64; v = dw2[t*64+c];
    } else if (u < 4032) {
        const int r = u-3744, t = r/32, c = r%32; v = dw3[t*32+c];
    } else if (u < 32704) {             // Bt0 [128][224]
        const int r = u-4032, n = r/224, c = r%224;
        if (c < 64)       v = pw0[(81+c)*128 + n];
        else if (c < 128) v = pw0[(145+(c-64))*128 + n];
        else if (c < 209) v = pw0[(c-128)*128 + n];
    } else if (u < 40896) {             // Bt1 [64][128]
        const int r = u-32704, n = r/128, c = r%128; v = pw1[c*64 + n];
    } else if (u < 42944) {             // Bt2 [32][64]
        const int r = u-40896, n = r/64, c = r%64; v = pw2[c*32 + n];
    } else {                            // Bt3 [16][32]
        const int r = u-42944, n = r/32, c = r%32; v = pw3[c*16 + n];
    }
    wout[u] = __float2bfloat16(v);
}

// ---------------------------------------------------------------------------
// prep2: f32 dw weights (stage0 permuted to [prv|nxt|cv|pad]) + fused BN*flow
// weights. fout: dwf0[2016] dwf1[1152] dwf2[576] dwf3[288] fwp[288] tb[18]
// ---------------------------------------------------------------------------
__global__ __launch_bounds__(256) void prep2_kernel(
    const float* __restrict__ dw0, const float* __restrict__ dw1,
    const float* __restrict__ dw2, const float* __restrict__ dw3,
    const float* __restrict__ bn_g, const float* __restrict__ bn_b,
    const float* __restrict__ bn_m, const float* __restrict__ bn_v,
    const float* __restrict__ fw, float* __restrict__ fout)
{
    const int u = blockIdx.x * 256 + threadIdx.x;
    if (u >= 4338) return;
    float v = 0.f;
    if (u < 2016) {
        const int t = u / 224, c = u % 224;
        if (c < 64)       v = dw0[t*209 + 81  + c];
        else if (c < 128) v = dw0[t*209 + 145 + (c-64)];
        else if (c < 209) v = dw0[t*209 + (c-128)];
    } else if (u < 3168) {
        const int r = u-2016, t = r/128, c = r%128; v = dw1[t*128+c];
    } else if (u < 3744) {
        const int r = u-3168, t = r/64, c = r%64; v = dw2[t*64+c];
    } else if (u < 4032) {
        const int r = u-3744, t = r/32, c = r%32; v = dw3[t*32+c];
    } else if (u < 4320) {              // fwp[t][c][s] = sc[c]*fw[t][c][s]
        const int r = u-4032, t = r/32, rem = r%32, c = rem >> 1, s = rem & 1;
        const float sc = bn_g[c] * rsqrtf(bn_v[c] + 1e-3f);
        v = sc * fw[t*32 + c*2 + s];
    } else {                            // tb[t][s] = sum_c sh[c]*fw[t][c][s]
        const int r = u-4320, t = r/2, s = r%2;
        float a = 0.f;
        for (int c = 0; c < 16; ++c) {
            const float sc = bn_g[c] * rsqrtf(bn_v[c] + 1e-3f);
            const float sh = bn_b[c] - bn_m[c] * sc;
            a += sh * fw[t*32 + c*2 + s];
        }
        v = a;
    }
    fout[u] = v;
}

// ---------------------------------------------------------------------------
// Cost volume v4: BARRIER-FREE main loop.
// sNxt LDS staging deleted: each lane loads its MFMA B-fragment column
// (nxt px = w0-4+mt*16+jt*16+ln15, ch {kq*8, 32+kq*8}) directly from global
// f32 and packs to bf16. Each nxt row is consumed by exactly one iteration,
// so LDS transpose bought nothing but 13 barriers and a 13.4 KB occupancy
// tax. sCv writes are wave-disjoint (mt row x dj column) -> only 2 barriers
// total (after zero-init, before epilogue). LDS 38.4->24.6 KB: 6 blocks/CU.
// xout nxt section written directly from the packed fragments.
// ---------------------------------------------------------------------------
template<int UNIFIED>
__global__ __launch_bounds__(256) void cost_mfma_kernel(
    const float* __restrict__ prv, const float* __restrict__ nxt,
    __hip_bfloat16* __restrict__ xout)
{
    constexpr int OST   = UNIFIED ? 224 : CVP;
    constexpr int CVOFF = UNIFIED ? 128 : 0;

    __shared__ __align__(16) short sCv[4][32][96];   // 24576 B — only LDS

    const int tid  = threadIdx.x;
    const int lane = tid & 63;
    const int wv   = tid >> 6;
    const int ln15 = lane & 15;
    const int kq   = lane >> 4;
    const int mt   = wv & 1;
    const int jt   = wv >> 1;

    const int bx = blockIdx.x;
    const int tw = bx % 6;
    const int th = (bx / 6) % 48;
    const int b  = bx / 288;
    const int w0 = tw * 32, h0 = th * 4;

    {
        const short8 z = {0,0,0,0,0,0,0,0};
#pragma unroll
        for (int t = 0; t < 6; ++t) {
            const int idx = tid + t * 256;
            const int row = idx / 384, rem = idx % 384;
            const int px = rem / 12, c8 = rem % 12;
            *(short8*)&sCv[row][px][c8 * 8] = z;
        }
    }

    short8 af0[4], af1[4];
    {
        const int apx = w0 + mt * 16 + ln15;
#pragma unroll
        for (int r4 = 0; r4 < 4; ++r4) {
            const float* ap = prv + (((size_t)b * HH + h0 + r4) * WW + apx) * CC0 + kq * 8;
            const float4 x0 = *(const float4*)(ap);
            const float4 x1 = *(const float4*)(ap + 4);
            const float4 x2 = *(const float4*)(ap + 32);
            const float4 x3 = *(const float4*)(ap + 36);
            af0[r4][0]=f2bf(x0.x); af0[r4][1]=f2bf(x0.y); af0[r4][2]=f2bf(x0.z); af0[r4][3]=f2bf(x0.w);
            af0[r4][4]=f2bf(x1.x); af0[r4][5]=f2bf(x1.y); af0[r4][6]=f2bf(x1.z); af0[r4][7]=f2bf(x1.w);
            af1[r4][0]=f2bf(x2.x); af1[r4][1]=f2bf(x2.y); af1[r4][2]=f2bf(x2.z); af1[r4][3]=f2bf(x2.w);
            af1[r4][4]=f2bf(x3.x); af1[r4][5]=f2bf(x3.y); af1[r4][6]=f2bf(x3.z); af1[r4][7]=f2bf(x3.w);
        }
    }

    // prv section of xout from fragments (jt==0 waves cover the full tile)
    if (UNIFIED && jt == 0) {
#pragma unroll
        for (int r4 = 0; r4 < 4; ++r4) {
            short* op = (short*)xout
                + (((size_t)b * HH + h0 + r4) * WW + w0 + mt * 16 + ln15) * OST
                + kq * 8;
            *(short8*)op = af0[r4];
            *(short8*)(op + 32) = af1[r4];
        }
    }

    __syncthreads();   // zero-init visible before any cv writes

    // lane's private nxt column: px gwb, ch {kq*8..+7, 32+kq*8..+7}
    const int gwb = w0 - 4 + mt * 16 + jt * 16 + ln15;
    const bool gok = ((unsigned)gwb < (unsigned)WW);
    const float* nxcol = nxt + ((size_t)b * HH * WW + gwb) * CC0 + kq * 8;

    const float4 fz = make_float4(0.f, 0.f, 0.f, 0.f);
    float4 c0 = fz, c1 = fz, c2 = fz, c3 = fz;
    float4 n0 = fz, n1 = fz, n2 = fz, n3 = fz;

    auto ldrow = [&](int y, float4& a0, float4& a1, float4& a2, float4& a3) {
        a0 = a1 = a2 = a3 = fz;
        if (gok && (unsigned)y < (unsigned)HH) {
            const float* p = nxcol + (size_t)y * (WW * CC0);
            a0 = *(const float4*)(p);
            a1 = *(const float4*)(p + 4);
            a2 = *(const float4*)(p + 32);
            a3 = *(const float4*)(p + 36);
        }
    };

    ldrow(h0 - 4, c0, c1, c2, c3);

    for (int i = 0; i < 12; ++i) {
        const int y = h0 - 4 + i;
        if (i < 11) ldrow(y + 1, n0, n1, n2, n3);

        if ((unsigned)y < (unsigned)HH) {
            short8 b0, b1;
            b0[0]=f2bf(c0.x); b0[1]=f2bf(c0.y); b0[2]=f2bf(c0.z); b0[3]=f2bf(c0.w);
            b0[4]=f2bf(c1.x); b0[5]=f2bf(c1.y); b0[6]=f2bf(c1.z); b0[7]=f2bf(c1.w);
            b1[0]=f2bf(c2.x); b1[1]=f2bf(c2.y); b1[2]=f2bf(c2.z); b1[3]=f2bf(c2.w);
            b1[4]=f2bf(c3.x); b1[5]=f2bf(c3.y); b1[6]=f2bf(c3.z); b1[7]=f2bf(c3.w);

            // nxt section of xout, straight from fragments (rows h0..h0+3)
            if (UNIFIED && i >= 4 && i < 8 && gwb >= w0 && gwb < w0 + 32) {
                short* op = (short*)xout
                    + (((size_t)b * HH + y) * WW + gwb) * OST + 64 + kq * 8;
                *(short8*)op = b0;
                *(short8*)(op + 32) = b1;
            }

#pragma unroll
            for (int r4 = 0; r4 < 4; ++r4) {
                const int rband = i - r4;   // == y - (h0+r4) + 4
                if ((unsigned)rband <= 8u) {
                    f32x4 acc = {0.f, 0.f, 0.f, 0.f};
                    acc = __builtin_amdgcn_mfma_f32_16x16x32_bf16(af0[r4], b0, acc, 0, 0, 0);
                    acc = __builtin_amdgcn_mfma_f32_16x16x32_bf16(af1[r4], b1, acc, 0, 0, 0);
#pragma unroll
                    for (int rr = 0; rr < 4; ++rr) {
                        const int m_local = kq * 4 + rr;
                        const int dj = jt * 16 + ln15 - m_local;
                        if ((unsigned)dj < 9u) {
                            float mv = acc[rr] * (1.0f / 64.0f);
                            mv = (mv > 0.f) ? mv : 0.1f * mv;
                            sCv[r4][mt * 16 + m_local][rband * 9 + dj] = f2bf(mv);
                        }
                    }
                }
            }
        }
        c0 = n0; c1 = n1; c2 = n2; c3 = n3;
    }

    __syncthreads();
    const size_t obase_blk = (((size_t)b * HH + h0) * WW + w0);
#pragma unroll
    for (int t = 0; t < 6; ++t) {
        const int idx = tid + t * 256;
        const int row = idx / 384, rem = idx % 384;
        const int px = rem / 12, c8 = rem % 12;
        short* op = (short*)xout + (obase_blk + (size_t)row * WW + px) * OST + CVOFF + c8 * 8;
        *(short8*)op = *(const short8*)&sCv[row][px][c8 * 8];
    }
}

// ---------------------------------------------------------------------------
// Fused sepconv v3: software-pipelined, granule-XOR-swizzled sIn
// (G(p,kb) = 4p + (kb ^ ((p>>1)&3)) — conflict-free depthwise ds_read_b128),
// staging address math hoisted out of the chunk loop.
// ---------------------------------------------------------------------------
template<int KP, int COUT, int MODE>
__global__ __launch_bounds__(256) void sepconv_mfma(
    const __hip_bfloat16* __restrict__ in,
    const float* __restrict__ prv, const float* __restrict__ nxt,
    const float* __restrict__ dwf,             // [9][KP] f32
    const __hip_bfloat16* __restrict__ Bt,     // [COUT][KP]
    const float* __restrict__ bias,
    __hip_bfloat16* __restrict__ out)
{
    constexpr int NC  = KP / 32;
    constexpr int NT  = COUT / 16;
    constexpr int WGN = (NT >= 2) ? 2 : 1;
    constexpr int WGM = 4 / WGN;
    constexpr int TM  = 8 / WGM;
    constexpr int TN  = NT / WGN;

    __shared__ __align__(16) short sIn[816 * 8];     // 13056 B, granule-swizzled
    __shared__ __align__(16) short sA[4][128][8];    //  8192 B

    const int tid  = threadIdx.x;
    const int lane = tid & 63;
    const int wv   = tid >> 6;
    const int ln15 = lane & 15;
    const int kq   = lane >> 4;
    const int wm   = wv % WGM;
    const int wn   = wv / WGM;

    const int bx = blockIdx.x;
    const int tw = bx % 6;
    const int th = (bx / 6) % 48;
    const int bb = bx / 288;
    const int w0 = tw * 32, h0 = th * 4;

    // depthwise mapping: wave-uniform k-slice (SGPR weights), lane = px
    const int dkbu = __builtin_amdgcn_readfirstlane(wv);
    const int dww  = lane & 31;
    const int dhh  = (lane >> 5) * 2;

    // fallback-path loader (MODE 1 only): unit u = (px p=u>>2, kblock kb=u&3)
    auto load_unit = [&](int u, int k0) -> short8 {
        const int kb = u & 3;
        const int p  = u >> 2;
        const int iw = p % 34, ih = p / 34;
        const int gw = w0 - 1 + iw, gh = h0 - 1 + ih;
        short8 v = {0,0,0,0,0,0,0,0};
        if ((unsigned)gw < (unsigned)WW && (unsigned)gh < (unsigned)HH) {
            const size_t pix = ((size_t)bb * HH + gh) * WW + gw;
            const int c0 = k0 + kb * 8;
            if (c0 < 64) {
                const float4* s = (const float4*)(prv + pix * 64 + c0);
                const float4 a = s[0], bq = s[1];
                v[0]=f2bf(a.x);  v[1]=f2bf(a.y);  v[2]=f2bf(a.z);  v[3]=f2bf(a.w);
                v[4]=f2bf(bq.x); v[5]=f2bf(bq.y); v[6]=f2bf(bq.z); v[7]=f2bf(bq.w);
            } else if (c0 < 128) {
                const float4* s = (const float4*)(nxt + pix * 64 + (c0 - 64));
                const float4 a = s[0], bq = s[1];
                v[0]=f2bf(a.x);  v[1]=f2bf(a.y);  v[2]=f2bf(a.z);  v[3]=f2bf(a.w);
                v[4]=f2bf(bq.x); v[5]=f2bf(bq.y); v[6]=f2bf(bq.z); v[7]=f2bf(bq.w);
            } else {
                v = *(const short8*)((const short*)in + pix * CVP + (c0 - 128));
            }
        }
        return v;
    };

    // chunk-invariant staging sources (MODE 0 fast path)
    const short* sp[4];
    bool sok[4];
#pragma unroll
    for (int t = 0; t < 4; ++t) {
        const int u = tid + t * 256;
        const int kb = u & 3, p = u >> 2;
        const int iw = p % 34, ih = p / 34;
        const int gw = w0 - 1 + iw, gh = h0 - 1 + ih;
        sok[t] = (u < 816) && ((unsigned)gw < (unsigned)WW) && ((unsigned)gh < (unsigned)HH);
        const size_t pix = ((size_t)bb * HH + gh) * WW + gw;
        sp[t] = (const short*)in + pix * KP + kb * 8;
    }

    f32x4 acc[TM][TN] = {};
    short8 pr[4];

    // prologue: prefetch chunk 0
#pragma unroll
    for (int t = 0; t < 4; ++t) {
        pr[t] = short8{0,0,0,0,0,0,0,0};
        if (MODE == 0) {
            if (sok[t]) pr[t] = *(const short8*)(sp[t]);
        } else {
            const int u = tid + t * 256;
            if (u < 816) pr[t] = load_unit(u, 0);
        }
    }

#pragma unroll
    for (int c = 0; c < NC; ++c) {
        const int k0 = c * 32;
        // --- commit prefetched staging to LDS (granule-swizzled) ---
#pragma unroll
        for (int t = 0; t < 4; ++t) {
            const int u = tid + t * 256;
            if (u < 816) {
                const int ug = u ^ ((u >> 3) & 3);
                *(short8*)(sIn + (size_t)ug * 8) = pr[t];
            }
        }
        __syncthreads();

        // --- issue next chunk's global loads (hidden behind dw+MFMA) ---
        if (c + 1 < NC) {
#pragma unroll
            for (int t = 0; t < 4; ++t) {
                pr[t] = short8{0,0,0,0,0,0,0,0};
                if (MODE == 0) {
                    if (sok[t]) pr[t] = *(const short8*)(sp[t] + k0 + 32);
                } else {
                    const int u = tid + t * 256;
                    if (u < 816) pr[t] = load_unit(u, k0 + 32);
                }
            }
        }
        // --- B-frags direct from global (Bt is L2-resident) ---
        short8 bfr[TN];
#pragma unroll
        for (int j = 0; j < TN; ++j) {
            const int n = (wn * TN + j) * 16 + ln15;
            bfr[j] = *(const short8*)((const short*)Bt + (size_t)n * KP + k0 + kq * 8);
        }

        // --- depthwise: 2 vertically-adjacent px, 8 ch; f32 SGPR weights ---
        {
            const float* wrow = dwf + k0 + dkbu * 8;
            const int pbase = dhh * 34 + dww;
            float r0[8] = {0,0,0,0,0,0,0,0};
            float r1[8] = {0,0,0,0,0,0,0,0};
#pragma unroll
            for (int dy = 0; dy < 4; ++dy) {
#pragma unroll
                for (int dx = 0; dx < 3; ++dx) {
                    const int p2 = pbase + dy * 34 + dx;
                    const int g  = p2 * 4 + (dkbu ^ ((p2 >> 1) & 3));
                    const short8 iv = *(const short8*)(sIn + (size_t)g * 8);
                    float fv[8];
                    cvt8(iv, fv);
                    if (dy < 3) {
#pragma unroll
                        for (int j = 0; j < 8; ++j)
                            r0[j] += fv[j] * wrow[(dy * 3 + dx) * KP + j];
                    }
                    if (dy >= 1) {
#pragma unroll
                        for (int j = 0; j < 8; ++j)
                            r1[j] += fv[j] * wrow[((dy - 1) * 3 + dx) * KP + j];
                    }
                }
            }
            const int px0 = dhh * 32 + dww;
            short8 o0, o1;
#pragma unroll
            for (int j = 0; j < 8; ++j) { o0[j] = f2bf(r0[j]); o1[j] = f2bf(r1[j]); }
            *(short8*)&sA[dkbu][px0 ^ (dkbu << 2)][0] = o0;
            *(short8*)&sA[dkbu][(px0 + 32) ^ (dkbu << 2)][0] = o1;
        }
        __syncthreads();

        // --- MFMA ---
        short8 af[TM];
#pragma unroll
        for (int i = 0; i < TM; ++i) {
            const int m = (wm * TM + i) * 16 + ln15;
            af[i] = *(const short8*)&sA[kq][m ^ (kq << 2)][0];
        }
#pragma unroll
        for (int i = 0; i < TM; ++i)
#pragma unroll
            for (int j = 0; j < TN; ++j)
                acc[i][j] = __builtin_amdgcn_mfma_f32_16x16x32_bf16(
                    af[i], bfr[j], acc[i][j], 0, 0, 0);
    }

#pragma unroll
    for (int j = 0; j < TN; ++j) {
        const int n = (wn * TN + j) * 16 + ln15;
        const float bj = bias[n];
#pragma unroll
        for (int i = 0; i < TM; ++i) {
#pragma unroll
            for (int r = 0; r < 4; ++r) {
                const int m  = (wm * TM + i) * 16 + kq * 4 + r;
                const int gh = h0 + (m >> 5), gw = w0 + (m & 31);
                const size_t gp = ((size_t)bb * HH + gh) * WW + gw;
                out[gp * COUT + n] = __float2bfloat16(mish_f(acc[i][j][r] + bj));
            }
        }
    }
}

// ---------------------------------------------------------------------------
// BN folded into flow conv: out = SC * sum_{taps in-bounds} (tb[t] + x.fwp[t])
// ---------------------------------------------------------------------------
__global__ __launch_bounds__(256) void bn_flow_kernel(
    const __hip_bfloat16* __restrict__ xin,
    const float* __restrict__ fwp, const float* __restrict__ tbv,
    float* __restrict__ out)
{
    const int pix = blockIdx.x * 256 + threadIdx.x;
    const int wq  = pix % WW;
    const int hq  = (pix / WW) % HH;
    const int bq  = pix / (WW * HH);
    float a0 = 0.f, a1 = 0.f;
#pragma unroll
    for (int dy = -1; dy <= 1; ++dy) {
        const int yy = hq + dy;
        if ((unsigned)yy >= HH) continue;
#pragma unroll
        for (int dx = -1; dx <= 1; ++dx) {
            const int xx = wq + dx;
            if ((unsigned)xx >= WW) continue;
            const int t = (dy + 1) * 3 + (dx + 1);
            a0 += tbv[t * 2 + 0];
            a1 += tbv[t * 2 + 1];
            const short* xp = (const short*)xin + (((size_t)bq * HH + yy) * WW + xx) * 16;
            const short8 v0 = *(const short8*)xp;
            const short8 v1 = *(const short8*)(xp + 8);
            float x[16];
            cvt8(v0, x); cvt8(v1, x + 8);
            const float* wp = fwp + t * 32;
#pragma unroll
            for (int c = 0; c < 16; ++c) {
                a0 += x[c] * wp[c * 2 + 0];
                a1 += x[c] * wp[c * 2 + 1];
            }
        }
    }
    const float SC = sqrtf((float)(HH * HH + WW * WW));
    out[(size_t)pix * 2 + 0] = SC * a0;
    out[(size_t)pix * 2 + 1] = SC * a1;
}

// ---------------------------------------------------------------------------
// Workspace:
// UNIFIED (ws >= ~208 MB): x0b[N][224] | t1[N][128] | wts bf16 | f32 wts
// FALLBACK (ws >= ~133 MB): cv[N][96]  | t1[N][128] | wts bf16 | f32 wts
// t2 = ws[0:N*64], t3 = t1, t4 = ws[N*64:N*80] in both.
// ---------------------------------------------------------------------------
extern "C" void kernel_launch(void* const* d_in, const int* in_sizes, int n_in,
                              void* d_out, int out_size, void* d_ws, size_t ws_size,
                              hipStream_t stream)
{
    const float* prv   = (const float*)d_in[0];
    const float* nxt   = (const float*)d_in[1];
    const float* dw0   = (const float*)d_in[2];
    const float* pw0   = (const float*)d_in[3];
    const float* b0    = (const float*)d_in[4];
    const float* dw1   = (const float*)d_in[5];
    const float* pw1   = (const float*)d_in[6];
    const float* b1    = (const float*)d_in[7];
    const float* dw2   = (const float*)d_in[8];
    const float* pw2   = (const float*)d_in[9];
    const float* b2    = (const float*)d_in[10];
    const float* dw3   = (const float*)d_in[11];
    const float* pw3   = (const float*)d_in[12];
    const float* b3    = (const float*)d_in[13];
    const float* bn_g  = (const float*)d_in[14];
    const float* bn_b  = (const float*)d_in[15];
    const float* bn_m  = (const float*)d_in[16];
    const float* bn_v  = (const float*)d_in[17];
    const float* fw    = (const float*)d_in[18];
    float* outp = (float*)d_out;

    const size_t N = (size_t)NPIX;
    __hip_bfloat16* ws = (__hip_bfloat16*)d_ws;

    const size_t need_uni = (N * 352 + 43456) * 2 + 4338 * 4;
    const bool uni = (ws_size >= need_uni);

    __hip_bfloat16* t1  = uni ? (ws + N * 224) : (ws + N * 96);
    __hip_bfloat16* wts = uni ? (ws + N * 352) : (ws + N * 224);
    __hip_bfloat16* t2  = ws;                    // aliases x0b/cv (dead then)
    __hip_bfloat16* t3  = t1;
    __hip_bfloat16* t4  = ws + N * 64;
    __hip_bfloat16* Bt0 = wts + 4032;
    __hip_bfloat16* Bt1 = wts + 32704;
    __hip_bfloat16* Bt2 = wts + 40896;
    __hip_bfloat16* Bt3 = wts + 42944;
    float* fwt = (float*)(wts + 43456);          // dwf0|dwf1|dwf2|dwf3|fwp|tb

    prep_kernel<<<170, 256, 0, stream>>>(dw0, pw0, dw1, pw1, dw2, pw2, dw3, pw3, wts);
    prep2_kernel<<<17, 256, 0, stream>>>(dw0, dw1, dw2, dw3,
                                         bn_g, bn_b, bn_m, bn_v, fw, fwt);
    if (uni) {
        cost_mfma_kernel<1><<<2304, 256, 0, stream>>>(prv, nxt, ws);
        sepconv_mfma<224, 128, 0><<<2304, 256, 0, stream>>>(ws, nullptr, nullptr,
                                                            fwt, Bt0, b0, t1);
    } else {
        cost_mfma_kernel<0><<<2304, 256, 0, stream>>>(prv, nxt, ws);
        sepconv_mfma<224, 128, 1><<<2304, 256, 0, stream>>>(ws, prv, nxt,
                                                            fwt, Bt0, b0, t1);
    }
    sepconv_mfma<128, 64, 0><<<2304, 256, 0, stream>>>(t1, nullptr, nullptr,
                                                       fwt + 2016, Bt1, b1, t2);
    sepconv_mfma<64, 32, 0><<<2304, 256, 0, stream>>>(t2, nullptr, nullptr,
                                                      fwt + 3168, Bt2, b2, t3);
    sepconv_mfma<32, 16, 0><<<2304, 256, 0, stream>>>(t3, nullptr, nullptr,
                                                      fwt + 3744, Bt3, b3, t4);
    bn_flow_kernel<<<NPIX / 256, 256, 0, stream>>>(t4, fwt + 4032, fwt + 4320, outp);
}

// Round 4
// 451.164 us; speedup vs baseline: 1.1559x; 1.0042x over previous
//
#include <hip/hip_runtime.h>
#include <hip/hip_bf16.h>

// Problem constants
#define BB 8
#define HH 192
#define WW 192
#define CC0 64
#define NPIX (BB*HH*WW) // 294912
#define NCV 81
#define CVP 96          // cv padded channels in fallback layout

typedef __attribute__((ext_vector_type(8))) short short8;
typedef __attribute__((ext_vector_type(4))) short short4v;
typedef __attribute__((ext_vector_type(4))) float f32x4;

__device__ __forceinline__ float bf2f(short s) {
    union { unsigned u; float f; } x; x.u = ((unsigned)(unsigned short)s) << 16; return x.f;
}
__device__ __forceinline__ short f2bf(float f) {
    __hip_bfloat16 h = __float2bfloat16(f);
    return *reinterpret_cast<short*>(&h);
}
__device__ __forceinline__ void cvt8(const short8 iv, float* fv) {
    const int* ip = (const int*)&iv;
#pragma unroll
    for (int e = 0; e < 4; ++e) {
        union { unsigned u; float f; } lo, hi;
        lo.u = ((unsigned)ip[e]) << 16;
        hi.u = ((unsigned)ip[e]) & 0xffff0000u;
        fv[2 * e] = lo.f; fv[2 * e + 1] = hi.f;
    }
}

__device__ __forceinline__ float mish_f(float v) {
    if (v > 20.0f) return v;
    const float u = __expf(v);
    const float n = u * (u + 2.0f);
    return v * n / (n + 2.0f);
}

// XCD-aware bijective block swizzle (nwg must be a multiple of 8).
// Consecutive logical tiles land on the same XCD -> halo/row overlap hits
// that XCD's L2 instead of a remote one.
__device__ __forceinline__ int xcd_swz(int bid, int nwg) {
    return (bid & 7) * (nwg >> 3) + (bid >> 3);
}

// ---------------------------------------------------------------------------
// Weight prep (bf16 Bt matrices, channel order [prv|nxt|cv|pad]) — as R4.
// ---------------------------------------------------------------------------
__global__ __launch_bounds__(256) void prep_kernel(
    const float* __restrict__ dw0, const float* __restrict__ pw0,
    const float* __restrict__ dw1, const float* __restrict__ pw1,
    const float* __restrict__ dw2, const float* __restrict__ pw2,
    const float* __restrict__ dw3, const float* __restrict__ pw3,
    __hip_bfloat16* __restrict__ wout)
{
    const int u = blockIdx.x * 256 + threadIdx.x;
    if (u >= 43456) return;
    float v = 0.f;
    if (u < 2016) {                     // legacy dwbf0 slot (unused, kept for layout)
        const int t = u / 224, c = u % 224;
        if (c < 64)       v = dw0[t*209 + 81  + c];
        else if (c < 128) v = dw0[t*209 + 145 + (c-64)];
        else if (c < 209) v = dw0[t*209 + (c-128)];
    } else if (u < 3168) {
        const int r = u-2016, t = r/128, c = r%128; v = dw1[t*128+c];
    } else if (u < 3744) {
        const int r = u-3168, t = r/64, c = r%64; v = dw2[t*64+c];
    } else if (u < 4032) {
        const int r = u-3744, t = r/32, c = r%32; v = dw3[t*32+c];
    } else if (u < 32704) {             // Bt0 [128][224]
        const int r = u-4032, n = r/224, c = r%224;
        if (c < 64)       v = pw0[(81+c)*128 + n];
        else if (c < 128) v = pw0[(145+(c-64))*128 + n];
        else if (c < 209) v = pw0[(c-128)*128 + n];
    } else if (u < 40896) {             // Bt1 [64][128]
        const int r = u-32704, n = r/128, c = r%128; v = pw1[c*64 + n];
    } else if (u < 42944) {             // Bt2 [32][64]
        const int r = u-40896, n = r/64, c = r%64; v = pw2[c*32 + n];
    } else {                            // Bt3 [16][32]
        const int r = u-42944, n = r/32, c = r%32; v = pw3[c*16 + n];
    }
    wout[u] = __float2bfloat16(v);
}

// ---------------------------------------------------------------------------
// prep2: f32 dw weights (stage0 permuted to [prv|nxt|cv|pad]) + fused BN*flow
// weights. fout: dwf0[2016] dwf1[1152] dwf2[576] dwf3[288] fwp[288] tb[18]
// ---------------------------------------------------------------------------
__global__ __launch_bounds__(256) void prep2_kernel(
    const float* __restrict__ dw0, const float* __restrict__ dw1,
    const float* __restrict__ dw2, const float* __restrict__ dw3,
    const float* __restrict__ bn_g, const float* __restrict__ bn_b,
    const float* __restrict__ bn_m, const float* __restrict__ bn_v,
    const float* __restrict__ fw, float* __restrict__ fout)
{
    const int u = blockIdx.x * 256 + threadIdx.x;
    if (u >= 4338) return;
    float v = 0.f;
    if (u < 2016) {
        const int t = u / 224, c = u % 224;
        if (c < 64)       v = dw0[t*209 + 81  + c];
        else if (c < 128) v = dw0[t*209 + 145 + (c-64)];
        else if (c < 209) v = dw0[t*209 + (c-128)];
    } else if (u < 3168) {
        const int r = u-2016, t = r/128, c = r%128; v = dw1[t*128+c];
    } else if (u < 3744) {
        const int r = u-3168, t = r/64, c = r%64; v = dw2[t*64+c];
    } else if (u < 4032) {
        const int r = u-3744, t = r/32, c = r%32; v = dw3[t*32+c];
    } else if (u < 4320) {              // fwp[t][c][s] = sc[c]*fw[t][c][s]
        const int r = u-4032, t = r/32, rem = r%32, c = rem >> 1, s = rem & 1;
        const float sc = bn_g[c] * rsqrtf(bn_v[c] + 1e-3f);
        v = sc * fw[t*32 + c*2 + s];
    } else {                            // tb[t][s] = sum_c sh[c]*fw[t][c][s]
        const int r = u-4320, t = r/2, s = r%2;
        float a = 0.f;
        for (int c = 0; c < 16; ++c) {
            const float sc = bn_g[c] * rsqrtf(bn_v[c] + 1e-3f);
            const float sh = bn_b[c] - bn_m[c] * sc;
            a += sh * fw[t*32 + c*2 + s];
        }
        v = a;
    }
    fout[u] = v;
}

// ---------------------------------------------------------------------------
// Cost volume v5: barrier-free main loop (v4) + 3-slot row pipeline
// (loads issued 2 iterations before consumption -> ~2x the latency-hide
// window of the 1-deep v4 pipeline) + XCD-aware block swizzle (vertically
// adjacent tiles share 8/12 nxt rows; keeping them on one XCD makes that
// overlap an L2 hit).
// ---------------------------------------------------------------------------
template<int UNIFIED>
__global__ __launch_bounds__(256) void cost_mfma_kernel(
    const float* __restrict__ prv, const float* __restrict__ nxt,
    __hip_bfloat16* __restrict__ xout)
{
    constexpr int OST   = UNIFIED ? 224 : CVP;
    constexpr int CVOFF = UNIFIED ? 128 : 0;

    __shared__ __align__(16) short sCv[4][32][96];   // 24576 B — only LDS

    const int tid  = threadIdx.x;
    const int lane = tid & 63;
    const int wv   = tid >> 6;
    const int ln15 = lane & 15;
    const int kq   = lane >> 4;
    const int mt   = wv & 1;
    const int jt   = wv >> 1;

    const int bx = xcd_swz(blockIdx.x, 2304);
    const int tw = bx % 6;
    const int th = (bx / 6) % 48;
    const int b  = bx / 288;
    const int w0 = tw * 32, h0 = th * 4;

    {
        const short8 z = {0,0,0,0,0,0,0,0};
#pragma unroll
        for (int t = 0; t < 6; ++t) {
            const int idx = tid + t * 256;
            const int row = idx / 384, rem = idx % 384;
            const int px = rem / 12, c8 = rem % 12;
            *(short8*)&sCv[row][px][c8 * 8] = z;
        }
    }

    short8 af0[4], af1[4];
    {
        const int apx = w0 + mt * 16 + ln15;
#pragma unroll
        for (int r4 = 0; r4 < 4; ++r4) {
            const float* ap = prv + (((size_t)b * HH + h0 + r4) * WW + apx) * CC0 + kq * 8;
            const float4 x0 = *(const float4*)(ap);
            const float4 x1 = *(const float4*)(ap + 4);
            const float4 x2 = *(const float4*)(ap + 32);
            const float4 x3 = *(const float4*)(ap + 36);
            af0[r4][0]=f2bf(x0.x); af0[r4][1]=f2bf(x0.y); af0[r4][2]=f2bf(x0.z); af0[r4][3]=f2bf(x0.w);
            af0[r4][4]=f2bf(x1.x); af0[r4][5]=f2bf(x1.y); af0[r4][6]=f2bf(x1.z); af0[r4][7]=f2bf(x1.w);
            af1[r4][0]=f2bf(x2.x); af1[r4][1]=f2bf(x2.y); af1[r4][2]=f2bf(x2.z); af1[r4][3]=f2bf(x2.w);
            af1[r4][4]=f2bf(x3.x); af1[r4][5]=f2bf(x3.y); af1[r4][6]=f2bf(x3.z); af1[r4][7]=f2bf(x3.w);
        }
    }

    // prv section of xout from fragments (jt==0 waves cover the full tile)
    if (UNIFIED && jt == 0) {
#pragma unroll
        for (int r4 = 0; r4 < 4; ++r4) {
            short* op = (short*)xout
                + (((size_t)b * HH + h0 + r4) * WW + w0 + mt * 16 + ln15) * OST
                + kq * 8;
            *(short8*)op = af0[r4];
            *(short8*)(op + 32) = af1[r4];
        }
    }

    __syncthreads();   // zero-init visible before any cv writes

    // lane's private nxt column: px gwb, ch {kq*8..+7, 32+kq*8..+7}
    const int gwb = w0 - 4 + mt * 16 + jt * 16 + ln15;
    const bool gok = ((unsigned)gwb < (unsigned)WW);
    const float* nxcol = nxt + ((size_t)b * HH * WW + gwb) * CC0 + kq * 8;
    const int dj0 = jt * 16 + ln15 - kq * 4;     // dj = dj0 - rr - (scatter base)
    const bool inw = (gwb >= w0) && (gwb < w0 + 32);

    const float4 fz = make_float4(0.f, 0.f, 0.f, 0.f);

    auto ldrow = [&](int y, float4& a0, float4& a1, float4& a2, float4& a3) {
        a0 = a1 = a2 = a3 = fz;
        if (gok && (unsigned)y < (unsigned)HH) {
            const float* p = nxcol + (size_t)y * (WW * CC0);
            a0 = *(const float4*)(p);
            a1 = *(const float4*)(p + 4);
            a2 = *(const float4*)(p + 32);
            a3 = *(const float4*)(p + 36);
        }
    };

    auto body = [&](int i, float4& a0, float4& a1, float4& a2, float4& a3,
                    float4& p0, float4& p1, float4& p2, float4& p3) {
        const int y = h0 - 4 + i;
        if (i < 10) ldrow(y + 2, p0, p1, p2, p3);   // 2-ahead prefetch
        if ((unsigned)y < (unsigned)HH) {
            short8 b0, b1;
            b0[0]=f2bf(a0.x); b0[1]=f2bf(a0.y); b0[2]=f2bf(a0.z); b0[3]=f2bf(a0.w);
            b0[4]=f2bf(a1.x); b0[5]=f2bf(a1.y); b0[6]=f2bf(a1.z); b0[7]=f2bf(a1.w);
            b1[0]=f2bf(a2.x); b1[1]=f2bf(a2.y); b1[2]=f2bf(a2.z); b1[3]=f2bf(a2.w);
            b1[4]=f2bf(a3.x); b1[5]=f2bf(a3.y); b1[6]=f2bf(a3.z); b1[7]=f2bf(a3.w);

            // nxt section of xout, straight from fragments (rows h0..h0+3)
            if (UNIFIED && i >= 4 && i < 8 && inw) {
                short* op = (short*)xout
                    + (((size_t)b * HH + y) * WW + gwb) * OST + 64 + kq * 8;
                *(short8*)op = b0;
                *(short8*)(op + 32) = b1;
            }

#pragma unroll
            for (int r4 = 0; r4 < 4; ++r4) {
                const int rband = i - r4;   // == y - (h0+r4) + 4
                if ((unsigned)rband <= 8u) {
                    f32x4 acc = {0.f, 0.f, 0.f, 0.f};
                    acc = __builtin_amdgcn_mfma_f32_16x16x32_bf16(af0[r4], b0, acc, 0, 0, 0);
                    acc = __builtin_amdgcn_mfma_f32_16x16x32_bf16(af1[r4], b1, acc, 0, 0, 0);
#pragma unroll
                    for (int rr = 0; rr < 4; ++rr) {
                        const int m_local = kq * 4 + rr;
                        const int dj = dj0 - rr;
                        if ((unsigned)dj < 9u) {
                            float mv = acc[rr] * (1.0f / 64.0f);
                            mv = (mv > 0.f) ? mv : 0.1f * mv;
                            sCv[r4][mt * 16 + m_local][rband * 9 + dj] = f2bf(mv);
                        }
                    }
                }
            }
        }
    };

    float4 s00, s01, s02, s03;   // slot 0
    float4 s10, s11, s12, s13;   // slot 1
    float4 s20, s21, s22, s23;   // slot 2

    ldrow(h0 - 4, s00, s01, s02, s03);
    ldrow(h0 - 3, s10, s11, s12, s13);

    for (int ii = 0; ii < 12; ii += 3) {
        body(ii + 0, s00, s01, s02, s03, s20, s21, s22, s23);
        body(ii + 1, s10, s11, s12, s13, s00, s01, s02, s03);
        body(ii + 2, s20, s21, s22, s23, s10, s11, s12, s13);
    }

    __syncthreads();
    const size_t obase_blk = (((size_t)b * HH + h0) * WW + w0);
#pragma unroll
    for (int t = 0; t < 6; ++t) {
        const int idx = tid + t * 256;
        const int row = idx / 384, rem = idx % 384;
        const int px = rem / 12, c8 = rem % 12;
        short* op = (short*)xout + (obase_blk + (size_t)row * WW + px) * OST + CVOFF + c8 * 8;
        *(short8*)op = *(const short8*)&sCv[row][px][c8 * 8];
    }
}

// ---------------------------------------------------------------------------
// Fused sepconv v4: software-pipelined, granule-XOR-swizzled sIn
// (G(p,kb) = 4p + (kb ^ ((p>>1)&3)) — conflict-free depthwise ds_read_b128),
// staging address math hoisted, XCD-aware block swizzle for halo L2 locality.
// ---------------------------------------------------------------------------
template<int KP, int COUT, int MODE>
__global__ __launch_bounds__(256) void sepconv_mfma(
    const __hip_bfloat16* __restrict__ in,
    const float* __restrict__ prv, const float* __restrict__ nxt,
    const float* __restrict__ dwf,             // [9][KP] f32
    const __hip_bfloat16* __restrict__ Bt,     // [COUT][KP]
    const float* __restrict__ bias,
    __hip_bfloat16* __restrict__ out)
{
    constexpr int NC  = KP / 32;
    constexpr int NT  = COUT / 16;
    constexpr int WGN = (NT >= 2) ? 2 : 1;
    constexpr int WGM = 4 / WGN;
    constexpr int TM  = 8 / WGM;
    constexpr int TN  = NT / WGN;

    __shared__ __align__(16) short sIn[816 * 8];     // 13056 B, granule-swizzled
    __shared__ __align__(16) short sA[4][128][8];    //  8192 B

    const int tid  = threadIdx.x;
    const int lane = tid & 63;
    const int wv   = tid >> 6;
    const int ln15 = lane & 15;
    const int kq   = lane >> 4;
    const int wm   = wv % WGM;
    const int wn   = wv / WGM;

    const int bx = xcd_swz(blockIdx.x, 2304);
    const int tw = bx % 6;
    const int th = (bx / 6) % 48;
    const int bb = bx / 288;
    const int w0 = tw * 32, h0 = th * 4;

    // depthwise mapping: wave-uniform k-slice (SGPR weights), lane = px
    const int dkbu = __builtin_amdgcn_readfirstlane(wv);
    const int dww  = lane & 31;
    const int dhh  = (lane >> 5) * 2;

    // fallback-path loader (MODE 1 only): unit u = (px p=u>>2, kblock kb=u&3)
    auto load_unit = [&](int u, int k0) -> short8 {
        const int kb = u & 3;
        const int p  = u >> 2;
        const int iw = p % 34, ih = p / 34;
        const int gw = w0 - 1 + iw, gh = h0 - 1 + ih;
        short8 v = {0,0,0,0,0,0,0,0};
        if ((unsigned)gw < (unsigned)WW && (unsigned)gh < (unsigned)HH) {
            const size_t pix = ((size_t)bb * HH + gh) * WW + gw;
            const int c0 = k0 + kb * 8;
            if (c0 < 64) {
                const float4* s = (const float4*)(prv + pix * 64 + c0);
                const float4 a = s[0], bq = s[1];
                v[0]=f2bf(a.x);  v[1]=f2bf(a.y);  v[2]=f2bf(a.z);  v[3]=f2bf(a.w);
                v[4]=f2bf(bq.x); v[5]=f2bf(bq.y); v[6]=f2bf(bq.z); v[7]=f2bf(bq.w);
            } else if (c0 < 128) {
                const float4* s = (const float4*)(nxt + pix * 64 + (c0 - 64));
                const float4 a = s[0], bq = s[1];
                v[0]=f2bf(a.x);  v[1]=f2bf(a.y);  v[2]=f2bf(a.z);  v[3]=f2bf(a.w);
                v[4]=f2bf(bq.x); v[5]=f2bf(bq.y); v[6]=f2bf(bq.z); v[7]=f2bf(bq.w);
            } else {
                v = *(const short8*)((const short*)in + pix * CVP + (c0 - 128));
            }
        }
        return v;
    };

    // chunk-invariant staging sources (MODE 0 fast path)
    const short* sp[4];
    bool sok[4];
#pragma unroll
    for (int t = 0; t < 4; ++t) {
        const int u = tid + t * 256;
        const int kb = u & 3, p = u >> 2;
        const int iw = p % 34, ih = p / 34;
        const int gw = w0 - 1 + iw, gh = h0 - 1 + ih;
        sok[t] = (u < 816) && ((unsigned)gw < (unsigned)WW) && ((unsigned)gh < (unsigned)HH);
        const size_t pix = ((size_t)bb * HH + gh) * WW + gw;
        sp[t] = (const short*)in + pix * KP + kb * 8;
    }

    f32x4 acc[TM][TN] = {};
    short8 pr[4];

    // prologue: prefetch chunk 0
#pragma unroll
    for (int t = 0; t < 4; ++t) {
        pr[t] = short8{0,0,0,0,0,0,0,0};
        if (MODE == 0) {
            if (sok[t]) pr[t] = *(const short8*)(sp[t]);
        } else {
            const int u = tid + t * 256;
            if (u < 816) pr[t] = load_unit(u, 0);
        }
    }

#pragma unroll
    for (int c = 0; c < NC; ++c) {
        const int k0 = c * 32;
        // --- commit prefetched staging to LDS (granule-swizzled) ---
#pragma unroll
        for (int t = 0; t < 4; ++t) {
            const int u = tid + t * 256;
            if (u < 816) {
                const int ug = u ^ ((u >> 3) & 3);
                *(short8*)(sIn + (size_t)ug * 8) = pr[t];
            }
        }
        __syncthreads();

        // --- issue next chunk's global loads (hidden behind dw+MFMA) ---
        if (c + 1 < NC) {
#pragma unroll
            for (int t = 0; t < 4; ++t) {
                pr[t] = short8{0,0,0,0,0,0,0,0};
                if (MODE == 0) {
                    if (sok[t]) pr[t] = *(const short8*)(sp[t] + k0 + 32);
                } else {
                    const int u = tid + t * 256;
                    if (u < 816) pr[t] = load_unit(u, k0 + 32);
                }
            }
        }
        // --- B-frags direct from global (Bt is L2-resident) ---
        short8 bfr[TN];
#pragma unroll
        for (int j = 0; j < TN; ++j) {
            const int n = (wn * TN + j) * 16 + ln15;
            bfr[j] = *(const short8*)((const short*)Bt + (size_t)n * KP + k0 + kq * 8);
        }

        // --- depthwise: 2 vertically-adjacent px, 8 ch; f32 SGPR weights ---
        {
            const float* wrow = dwf + k0 + dkbu * 8;
            const int pbase = dhh * 34 + dww;
            float r0[8] = {0,0,0,0,0,0,0,0};
            float r1[8] = {0,0,0,0,0,0,0,0};
#pragma unroll
            for (int dy = 0; dy < 4; ++dy) {
#pragma unroll
                for (int dx = 0; dx < 3; ++dx) {
                    const int p2 = pbase + dy * 34 + dx;
                    const int g  = p2 * 4 + (dkbu ^ ((p2 >> 1) & 3));
                    const short8 iv = *(const short8*)(sIn + (size_t)g * 8);
                    float fv[8];
                    cvt8(iv, fv);
                    if (dy < 3) {
#pragma unroll
                        for (int j = 0; j < 8; ++j)
                            r0[j] += fv[j] * wrow[(dy * 3 + dx) * KP + j];
                    }
                    if (dy >= 1) {
#pragma unroll
                        for (int j = 0; j < 8; ++j)
                            r1[j] += fv[j] * wrow[((dy - 1) * 3 + dx) * KP + j];
                    }
                }
            }
            const int px0 = dhh * 32 + dww;
            short8 o0, o1;
#pragma unroll
            for (int j = 0; j < 8; ++j) { o0[j] = f2bf(r0[j]); o1[j] = f2bf(r1[j]); }
            *(short8*)&sA[dkbu][px0 ^ (dkbu << 2)][0] = o0;
            *(short8*)&sA[dkbu][(px0 + 32) ^ (dkbu << 2)][0] = o1;
        }
        __syncthreads();

        // --- MFMA ---
        short8 af[TM];
#pragma unroll
        for (int i = 0; i < TM; ++i) {
            const int m = (wm * TM + i) * 16 + ln15;
            af[i] = *(const short8*)&sA[kq][m ^ (kq << 2)][0];
        }
#pragma unroll
        for (int i = 0; i < TM; ++i)
#pragma unroll
            for (int j = 0; j < TN; ++j)
                acc[i][j] = __builtin_amdgcn_mfma_f32_16x16x32_bf16(
                    af[i], bfr[j], acc[i][j], 0, 0, 0);
    }

#pragma unroll
    for (int j = 0; j < TN; ++j) {
        const int n = (wn * TN + j) * 16 + ln15;
        const float bj = bias[n];
#pragma unroll
        for (int i = 0; i < TM; ++i) {
#pragma unroll
            for (int r = 0; r < 4; ++r) {
                const int m  = (wm * TM + i) * 16 + kq * 4 + r;
                const int gh = h0 + (m >> 5), gw = w0 + (m & 31);
                const size_t gp = ((size_t)bb * HH + gh) * WW + gw;
                out[gp * COUT + n] = __float2bfloat16(mish_f(acc[i][j][r] + bj));
            }
        }
    }
}

// ---------------------------------------------------------------------------
// BN folded into flow conv: out = SC * sum_{taps in-bounds} (tb[t] + x.fwp[t])
// ---------------------------------------------------------------------------
__global__ __launch_bounds__(256) void bn_flow_kernel(
    const __hip_bfloat16* __restrict__ xin,
    const float* __restrict__ fwp, const float* __restrict__ tbv,
    float* __restrict__ out)
{
    const int pix = xcd_swz(blockIdx.x, NPIX / 256) * 256 + threadIdx.x;
    const int wq  = pix % WW;
    const int hq  = (pix / WW) % HH;
    const int bq  = pix / (WW * HH);
    float a0 = 0.f, a1 = 0.f;
#pragma unroll
    for (int dy = -1; dy <= 1; ++dy) {
        const int yy = hq + dy;
        if ((unsigned)yy >= HH) continue;
#pragma unroll
        for (int dx = -1; dx <= 1; ++dx) {
            const int xx = wq + dx;
            if ((unsigned)xx >= WW) continue;
            const int t = (dy + 1) * 3 + (dx + 1);
            a0 += tbv[t * 2 + 0];
            a1 += tbv[t * 2 + 1];
            const short* xp = (const short*)xin + (((size_t)bq * HH + yy) * WW + xx) * 16;
            const short8 v0 = *(const short8*)xp;
            const short8 v1 = *(const short8*)(xp + 8);
            float x[16];
            cvt8(v0, x); cvt8(v1, x + 8);
            const float* wp = fwp + t * 32;
#pragma unroll
            for (int c = 0; c < 16; ++c) {
                a0 += x[c] * wp[c * 2 + 0];
                a1 += x[c] * wp[c * 2 + 1];
            }
        }
    }
    const float SC = sqrtf((float)(HH * HH + WW * WW));
    out[(size_t)pix * 2 + 0] = SC * a0;
    out[(size_t)pix * 2 + 1] = SC * a1;
}

// ---------------------------------------------------------------------------
// Workspace:
// UNIFIED (ws >= ~208 MB): x0b[N][224] | t1[N][128] | wts bf16 | f32 wts
// FALLBACK (ws >= ~133 MB): cv[N][96]  | t1[N][128] | wts bf16 | f32 wts
// t2 = ws[0:N*64], t3 = t1, t4 = ws[N*64:N*80] in both.
// ---------------------------------------------------------------------------
extern "C" void kernel_launch(void* const* d_in, const int* in_sizes, int n_in,
                              void* d_out, int out_size, void* d_ws, size_t ws_size,
                              hipStream_t stream)
{
    const float* prv   = (const float*)d_in[0];
    const float* nxt   = (const float*)d_in[1];
    const float* dw0   = (const float*)d_in[2];
    const float* pw0   = (const float*)d_in[3];
    const float* b0    = (const float*)d_in[4];
    const float* dw1   = (const float*)d_in[5];
    const float* pw1   = (const float*)d_in[6];
    const float* b1    = (const float*)d_in[7];
    const float* dw2   = (const float*)d_in[8];
    const float* pw2   = (const float*)d_in[9];
    const float* b2    = (const float*)d_in[10];
    const float* dw3   = (const float*)d_in[11];
    const float* pw3   = (const float*)d_in[12];
    const float* b3    = (const float*)d_in[13];
    const float* bn_g  = (const float*)d_in[14];
    const float* bn_b  = (const float*)d_in[15];
    const float* bn_m  = (const float*)d_in[16];
    const float* bn_v  = (const float*)d_in[17];
    const float* fw    = (const float*)d_in[18];
    float* outp = (float*)d_out;

    const size_t N = (size_t)NPIX;
    __hip_bfloat16* ws = (__hip_bfloat16*)d_ws;

    const size_t need_uni = (N * 352 + 43456) * 2 + 4338 * 4;
    const bool uni = (ws_size >= need_uni);

    __hip_bfloat16* t1  = uni ? (ws + N * 224) : (ws + N * 96);
    __hip_bfloat16* wts = uni ? (ws + N * 352) : (ws + N * 224);
    __hip_bfloat16* t2  = ws;                    // aliases x0b/cv (dead then)
    __hip_bfloat16* t3  = t1;
    __hip_bfloat16* t4  = ws + N * 64;
    __hip_bfloat16* Bt0 = wts + 4032;
    __hip_bfloat16* Bt1 = wts + 32704;
    __hip_bfloat16* Bt2 = wts + 40896;
    __hip_bfloat16* Bt3 = wts + 42944;
    float* fwt = (float*)(wts + 43456);          // dwf0|dwf1|dwf2|dwf3|fwp|tb

    prep_kernel<<<170, 256, 0, stream>>>(dw0, pw0, dw1, pw1, dw2, pw2, dw3, pw3, wts);
    prep2_kernel<<<17, 256, 0, stream>>>(dw0, dw1, dw2, dw3,
                                         bn_g, bn_b, bn_m, bn_v, fw, fwt);
    if (uni) {
        cost_mfma_kernel<1><<<2304, 256, 0, stream>>>(prv, nxt, ws);
        sepconv_mfma<224, 128, 0><<<2304, 256, 0, stream>>>(ws, nullptr, nullptr,
                                                            fwt, Bt0, b0, t1);
    } else {
        cost_mfma_kernel<0><<<2304, 256, 0, stream>>>(prv, nxt, ws);
        sepconv_mfma<224, 128, 1><<<2304, 256, 0, stream>>>(ws, prv, nxt,
                                                            fwt, Bt0, b0, t1);
    }
    sepconv_mfma<128, 64, 0><<<2304, 256, 0, stream>>>(t1, nullptr, nullptr,
                                                       fwt + 2016, Bt1, b1, t2);
    sepconv_mfma<64, 32, 0><<<2304, 256, 0, stream>>>(t2, nullptr, nullptr,
                                                      fwt + 3168, Bt2, b2, t3);
    sepconv_mfma<32, 16, 0><<<2304, 256, 0, stream>>>(t3, nullptr, nullptr,
                                                      fwt + 3744, Bt3, b3, t4);
    bn_flow_kernel<<<NPIX / 256, 256, 0, stream>>>(t4, fwt + 4032, fwt + 4320, outp);
}